// Round 4
// baseline (2301.582 us; speedup 1.0000x reference)
//
#include <hip/hip_runtime.h>
#include <hip/hip_fp16.h>
#include <cstddef>

#define BB    4
#define NN    10000
#define EE    160000
#define BN    40000      // BB*NN
#define HISTC 8
#define PREDC 12
#define TSTEP 20         // HIST+PRED
#define FEX   8
#define HIDC  64
#define EHID  32
#define EOUTC 30
#define GOUTC 13
#define GINC  22         // GOUTC + 9

typedef float v2f __attribute__((ext_vector_type(2)));

__device__ __forceinline__ float fast_rcp(float x) { return __builtin_amdgcn_rcpf(x); }
__device__ __forceinline__ float sigm(float x) {
    return fast_rcp(1.0f + __expf(-x));
}
__device__ __forceinline__ v2f sigm2(v2f x) {
    v2f r; r.x = sigm(x.x); r.y = sigm(x.y); return r;
}
__device__ __forceinline__ float tanh_fast(float x) {
    x = fminf(fmaxf(x, -15.0f), 15.0f);
    float e = __expf(2.0f * x);
    return (e - 1.0f) * fast_rcp(e + 1.0f);
}

// ---------------- edge_attr stats: stage 1 (per-block partials) ---------------
__global__ __launch_bounds__(256) void stats1_kernel(const float* __restrict__ ea,
                                                     double* __restrict__ part) {
    __shared__ double sm[256][4];
    int tid = threadIdx.x;
    double s0 = 0, s1 = 0, q0 = 0, q1 = 0;
    for (int e = blockIdx.x * 256 + tid; e < EE; e += 256 * 256) {
        float2 v = reinterpret_cast<const float2*>(ea)[e];
        double v0 = (double)v.x, v1 = (double)v.y;
        s0 += v0; q0 += v0 * v0;
        s1 += v1; q1 += v1 * v1;
    }
    sm[tid][0] = s0; sm[tid][1] = s1; sm[tid][2] = q0; sm[tid][3] = q1;
    __syncthreads();
    for (int off = 128; off > 0; off >>= 1) {
        if (tid < off)
            for (int k = 0; k < 4; k++) sm[tid][k] += sm[tid + off][k];
        __syncthreads();
    }
    if (tid == 0) {
        part[blockIdx.x * 4 + 0] = sm[0][0];
        part[blockIdx.x * 4 + 1] = sm[0][1];
        part[blockIdx.x * 4 + 2] = sm[0][2];
        part[blockIdx.x * 4 + 3] = sm[0][3];
    }
}

__global__ __launch_bounds__(256) void stats2_kernel(const double* __restrict__ part,
                                                     float* __restrict__ stats) {
    __shared__ double sm[256][4];
    int tid = threadIdx.x;
    sm[tid][0] = part[tid * 4 + 0];
    sm[tid][1] = part[tid * 4 + 1];
    sm[tid][2] = part[tid * 4 + 2];
    sm[tid][3] = part[tid * 4 + 3];
    __syncthreads();
    for (int off = 128; off > 0; off >>= 1) {
        if (tid < off)
            for (int k = 0; k < 4; k++) sm[tid][k] += sm[tid + off][k];
        __syncthreads();
    }
    if (tid == 0) {
        double m0 = sm[0][0] / EE, m1 = sm[0][1] / EE;
        double v0 = (sm[0][2] - sm[0][0] * sm[0][0] / EE) / (double)(EE - 1);
        double v1 = (sm[0][3] - sm[0][1] * sm[0][1] / EE) / (double)(EE - 1);
        float sd0 = fmaxf((float)sqrt(v0 > 0 ? v0 : 0.0), 1e-6f);
        float sd1 = fmaxf((float)sqrt(v1 > 0 ? v1 : 0.0), 1e-6f);
        stats[0] = (float)m0; stats[1] = (float)m1;
        stats[2] = 1.0f / sd0; stats[3] = 1.0f / sd1;
    }
}

// ---------------- per-edge precompute: epre2 = {1/dist, direc}; ev(fp16) ------
// ev[e][o] = ean0*W1[18][o] + ean1*W1[19][o] + b1[o]
__global__ __launch_bounds__(256) void edgepre_kernel(
    const float* __restrict__ ea, const float* __restrict__ stats,
    const float* __restrict__ ew1, const float* __restrict__ eb1,
    float2* __restrict__ epre2, __half* __restrict__ ev)
{
    __shared__ float w18[EHID], w19[EHID], b1s[EHID];
    if (threadIdx.x < EHID) {
        w18[threadIdx.x] = ew1[18 * EHID + threadIdx.x];
        w19[threadIdx.x] = ew1[19 * EHID + threadIdx.x];
        b1s[threadIdx.x] = eb1[threadIdx.x];
    }
    __syncthreads();
    int e = blockIdx.x * 256 + threadIdx.x;
    if (e >= EE) return;
    float2 v = reinterpret_cast<const float2*>(ea)[e];
    float ean0 = (v.x - stats[0]) * stats[2];
    float ean1 = (v.y - stats[1]) * stats[3];
    float2 p; p.x = 1.0f / fmaxf(v.x, 1e-3f); p.y = v.y;
    epre2[e] = p;
    alignas(16) __half tmp[EHID];
    #pragma unroll
    for (int o = 0; o < EHID; o++)
        tmp[o] = __float2half(ean0 * w18[o] + ean1 * w19[o] + b1s[o]);
    uint4* dst = reinterpret_cast<uint4*>(ev + (size_t)e * EHID);
    const uint4* src = reinterpret_cast<const uint4*>(tmp);
    dst[0] = src[0]; dst[1] = src[1]; dst[2] = src[2]; dst[3] = src[3];
}

// ---------------- xn init from pm25_hist[:, -1] -------------------------------
__global__ void initxn_kernel(const float* __restrict__ pm, float* __restrict__ xn) {
    int i = blockIdx.x * 256 + threadIdx.x;
    if (i >= BN) return;
    int b = i / NN, n = i - b * NN;
    xn[i] = pm[(b * HISTC + (HISTC - 1)) * NN + n];
}

// ---------------- CSR build (once per call) -----------------------------------
__global__ void hist_kernel(const int* __restrict__ eidx,
                            int* __restrict__ deg_t, int* __restrict__ deg_s) {
    int e = blockIdx.x * 256 + threadIdx.x;
    if (e >= EE) return;
    atomicAdd(&deg_s[eidx[e]], 1);
    atomicAdd(&deg_t[eidx[EE + e]], 1);
}

__global__ __launch_bounds__(1024) void scan_kernel(
    const int* __restrict__ deg_t, const int* __restrict__ deg_s,
    int* __restrict__ off_t, int* __restrict__ off_s,
    int* __restrict__ cnt_t, int* __restrict__ cnt_s)
{
    __shared__ int pt[1024], ps[1024];
    int tid = threadIdx.x;
    int base = tid * 10;
    int st = 0, ss = 0;
    for (int k = 0; k < 10; k++) {
        int i = base + k;
        if (i < NN) { st += deg_t[i]; ss += deg_s[i]; }
    }
    pt[tid] = st; ps[tid] = ss;
    __syncthreads();
    for (int off = 1; off < 1024; off <<= 1) {
        int vt = (tid >= off) ? pt[tid - off] : 0;
        int vs = (tid >= off) ? ps[tid - off] : 0;
        __syncthreads();
        pt[tid] += vt; ps[tid] += vs;
        __syncthreads();
    }
    int ext = (tid == 0) ? 0 : pt[tid - 1];
    int exs = (tid == 0) ? 0 : ps[tid - 1];
    for (int k = 0; k < 10; k++) {
        int i = base + k;
        if (i < NN) {
            off_t[i] = ext; cnt_t[i] = ext;
            off_s[i] = exs; cnt_s[i] = exs;
            ext += deg_t[i]; exs += deg_s[i];
        }
    }
    if (tid == 0) { off_t[NN] = EE; off_s[NN] = EE; }
}

__global__ void fill_kernel(const int* __restrict__ eidx,
                            int* __restrict__ cnt_t, int* __restrict__ cnt_s,
                            int* __restrict__ pos_t, int* __restrict__ pos_s)
{
    int e = blockIdx.x * 256 + threadIdx.x;
    if (e >= EE) return;
    int s = eidx[e];
    int g = eidx[EE + e];
    pos_t[e] = atomicAdd(&cnt_t[g], 1);
    pos_s[e] = atomicAdd(&cnt_s[s], 1);
}

// ---------------- per-step node precompute ------------------------------------
// preS[i][o] = sum_{k=0..8} x[k]*W1[k][o];  preT[i][o] = sum_k x[k]*W1[9+k][o]
// wind2[i] = {3*relu(speed), wdir_rad}
__global__ __launch_bounds__(256) void pre_kernel(
    const float* __restrict__ xn, const float* __restrict__ feature, int t,
    const float* __restrict__ ew1,
    const float* __restrict__ wmean, const float* __restrict__ wstd,
    float* __restrict__ preS, float* __restrict__ preT, float2* __restrict__ wind2)
{
    __shared__ alignas(16) float w1s[18 * EHID];
    for (int i = threadIdx.x; i < 18 * EHID; i += 256) w1s[i] = ew1[i];
    __syncthreads();
    int i = blockIdx.x * 256 + threadIdx.x;
    if (i >= BN) return;
    int b = i / NN, n = i - b * NN;
    float x[9];
    x[0] = xn[i];
    {
        const float4* fp = reinterpret_cast<const float4*>(
            feature + (((size_t)b * TSTEP + HISTC + t) * NN + n) * FEX);
        float4 u = fp[0], v = fp[1];
        x[1] = u.x; x[2] = u.y; x[3] = u.z; x[4] = u.w;
        x[5] = v.x; x[6] = v.y; x[7] = v.z; x[8] = v.w;
    }
    float4* oS = reinterpret_cast<float4*>(preS + (size_t)i * EHID);
    float4* oT = reinterpret_cast<float4*>(preT + (size_t)i * EHID);
    #pragma unroll
    for (int o4 = 0; o4 < 8; o4++) {
        float4 aS = {0.f, 0.f, 0.f, 0.f}, aT = {0.f, 0.f, 0.f, 0.f};
        #pragma unroll
        for (int k = 0; k < 9; k++) {
            float4 wS = reinterpret_cast<const float4*>(&w1s[k * EHID])[o4];
            float4 wT = reinterpret_cast<const float4*>(&w1s[(9 + k) * EHID])[o4];
            aS.x += x[k] * wS.x; aS.y += x[k] * wS.y; aS.z += x[k] * wS.z; aS.w += x[k] * wS.w;
            aT.x += x[k] * wT.x; aT.y += x[k] * wT.y; aT.z += x[k] * wT.z; aT.w += x[k] * wT.w;
        }
        oS[o4] = aS; oT[o4] = aT;
    }
    float sd0 = fmaxf(wstd[0], 1e-6f), sd1 = fmaxf(wstd[1], 1e-6f);
    float speed = fmaxf(x[7] * sd0 + wmean[0], 0.f);
    float wdir  = (x[8] * sd1 + wmean[1]) * 0.017453292519943295f;
    float2 wv; wv.x = 3.0f * speed; wv.y = wdir;
    wind2[i] = wv;
}

// ---------------- edge MLP (layers 2,3 + folded n_w) --------------------------
// grid (EE/256, 2); blockIdx.y = bA; thread handles batches bA and bA+2 via
// packed float2 (v_pk_fma_f32). Layer 1 = table adds.
__global__ __launch_bounds__(256) void edge_kernel(
    const int* __restrict__ eidx, const float2* __restrict__ epre2,
    const __half* __restrict__ ev,
    const float* __restrict__ preS, const float* __restrict__ preT,
    const float2* __restrict__ wind2,
    const int* __restrict__ pos_t, const int* __restrict__ pos_s,
    const float* __restrict__ ew1, const float* __restrict__ ew2,
    const float* __restrict__ eb2, const float* __restrict__ nw,
    __half* __restrict__ h3t, __half* __restrict__ h3s)
{
    __shared__ alignas(16) float w2t[EOUTC * EHID];    // [o][k]
    __shared__ alignas(16) float nws16[EOUTC * 16];    // [o][j] padded
    __shared__ alignas(16) float w20[EHID];
    __shared__ float b2s[EOUTC];
    for (int i = threadIdx.x; i < EOUTC * EHID; i += 256) {
        int o = i / EHID, k = i - o * EHID;
        w2t[i] = ew2[k * EOUTC + o];
    }
    for (int i = threadIdx.x; i < EOUTC * 16; i += 256) {
        int o = i >> 4, j = i & 15;
        nws16[i] = (j < GOUTC) ? nw[o * GOUTC + j] : 0.f;
    }
    if (threadIdx.x < EHID) w20[threadIdx.x] = ew1[20 * EHID + threadIdx.x];
    if (threadIdx.x < EOUTC) b2s[threadIdx.x] = eb2[threadIdx.x];
    __syncthreads();

    int e = blockIdx.x * 256 + threadIdx.x;
    if (e >= EE) return;
    int bA = blockIdx.y;
    int bB = bA + 2;
    int s = eidx[e];
    int g = eidx[EE + e];
    int pt = pos_t[e];
    int ps = pos_s[e];
    float2 p2 = epre2[e];          // {1/dist, direc}

    alignas(16) __half evh[EHID];
    {
        uint4* d = reinterpret_cast<uint4*>(evh);
        const uint4* srcv = reinterpret_cast<const uint4*>(ev + (size_t)e * EHID);
        d[0] = srcv[0]; d[1] = srcv[1]; d[2] = srcv[2]; d[3] = srcv[3];
    }

    size_t iSA = (size_t)bA * NN + s, iTA = (size_t)bA * NN + g;
    size_t iSB = (size_t)bB * NN + s, iTB = (size_t)bB * NN + g;
    float2 wA = wind2[iSA];
    float2 wB = wind2[iSB];
    v2f ew;
    ew.x = fmaxf(wA.x * __cosf(fabsf(p2.y - wA.y)) * p2.x, 0.f);
    ew.y = fmaxf(wB.x * __cosf(fabsf(p2.y - wB.y)) * p2.x, 0.f);

    const float4* pSA = reinterpret_cast<const float4*>(preS + iSA * EHID);
    const float4* pTA = reinterpret_cast<const float4*>(preT + iTA * EHID);
    const float4* pSB = reinterpret_cast<const float4*>(preS + iSB * EHID);
    const float4* pTB = reinterpret_cast<const float4*>(preT + iTB * EHID);

    v2f h1v[EHID];
    #pragma unroll
    for (int o4 = 0; o4 < 8; o4++) {
        float4 sa = pSA[o4], ta = pTA[o4], sb = pSB[o4], tb = pTB[o4];
        float4 wv = reinterpret_cast<const float4*>(w20)[o4];
        float evx0 = __half2float(evh[4*o4+0]);
        float evx1 = __half2float(evh[4*o4+1]);
        float evx2 = __half2float(evh[4*o4+2]);
        float evx3 = __half2float(evh[4*o4+3]);
        v2f u;
        u.x = sa.x + ta.x + evx0; u.y = sb.x + tb.x + evx0;
        u += wv.x * ew; h1v[4*o4+0] = sigm2(u);
        u.x = sa.y + ta.y + evx1; u.y = sb.y + tb.y + evx1;
        u += wv.y * ew; h1v[4*o4+1] = sigm2(u);
        u.x = sa.z + ta.z + evx2; u.y = sb.z + tb.z + evx2;
        u += wv.z * ew; h1v[4*o4+2] = sigm2(u);
        u.x = sa.w + ta.w + evx3; u.y = sb.w + tb.w + evx3;
        u += wv.w * ew; h1v[4*o4+3] = sigm2(u);
    }

    v2f h3v[GOUTC];
    #pragma unroll
    for (int j = 0; j < GOUTC; j++) { h3v[j].x = 0.f; h3v[j].y = 0.f; }

    for (int o = 0; o < EOUTC; o++) {
        v2f acc; acc.x = b2s[o]; acc.y = b2s[o];
        const float4* wr = reinterpret_cast<const float4*>(&w2t[o * EHID]);
        #pragma unroll
        for (int q = 0; q < 8; q++) {
            float4 wq = wr[q];
            acc += wq.x * h1v[4*q+0];
            acc += wq.y * h1v[4*q+1];
            acc += wq.z * h1v[4*q+2];
            acc += wq.w * h1v[4*q+3];
        }
        v2f h2 = sigm2(acc);
        const float4* nr = reinterpret_cast<const float4*>(&nws16[o * 16]);
        float4 n0 = nr[0], n1 = nr[1], n2 = nr[2], n3 = nr[3];
        h3v[0]  += n0.x * h2;  h3v[1]  += n0.y * h2;
        h3v[2]  += n0.z * h2;  h3v[3]  += n0.w * h2;
        h3v[4]  += n1.x * h2;  h3v[5]  += n1.y * h2;
        h3v[6]  += n1.z * h2;  h3v[7]  += n1.w * h2;
        h3v[8]  += n2.x * h2;  h3v[9]  += n2.y * h2;
        h3v[10] += n2.z * h2;  h3v[11] += n2.w * h2;
        h3v[12] += n3.x * h2;
    }

    alignas(16) __half rA[16], rB[16];
    #pragma unroll
    for (int j = 0; j < GOUTC; j++) {
        rA[j] = __float2half(h3v[j].x);
        rB[j] = __float2half(h3v[j].y);
    }
    #pragma unroll
    for (int j = GOUTC; j < 16; j++) { rA[j] = __float2half(0.f); rB[j] = __float2half(0.f); }
    uint4 rA0 = reinterpret_cast<const uint4*>(rA)[0];
    uint4 rA1 = reinterpret_cast<const uint4*>(rA)[1];
    uint4 rB0 = reinterpret_cast<const uint4*>(rB)[0];
    uint4 rB1 = reinterpret_cast<const uint4*>(rB)[1];
    {
        __half* oA = h3t + ((size_t)bA * EE + pt) * 16;
        __half* oB = h3t + ((size_t)bB * EE + pt) * 16;
        reinterpret_cast<uint4*>(oA)[0] = rA0;
        reinterpret_cast<uint4*>(oA)[1] = rA1;
        reinterpret_cast<uint4*>(oB)[0] = rB0;
        reinterpret_cast<uint4*>(oB)[1] = rB1;
    }
    {
        __half* oA = h3s + ((size_t)bA * EE + ps) * 16;
        __half* oB = h3s + ((size_t)bB * EE + ps) * 16;
        reinterpret_cast<uint4*>(oA)[0] = rA0;
        reinterpret_cast<uint4*>(oA)[1] = rA1;
        reinterpret_cast<uint4*>(oB)[0] = rB0;
        reinterpret_cast<uint4*>(oB)[1] = rB1;
    }
}

// ---------------- gather: agg13[b][n][ch] = sum_in h3t - sum_out h3s ----------
__global__ __launch_bounds__(256) void gather_kernel(
    const __half* __restrict__ h3t, const __half* __restrict__ h3s,
    const int* __restrict__ off_t, const int* __restrict__ off_s,
    float* __restrict__ agg)
{
    int n = (blockIdx.x * 256 + threadIdx.x) >> 6;
    if (n >= NN) return;
    n = __builtin_amdgcn_readfirstlane(n);
    int lane = threadIdx.x & 63;
    int b = lane >> 4, ch = lane & 15;
    const __half* ht = h3t + (size_t)b * EE * 16 + ch;
    const __half* hs = h3s + (size_t)b * EE * 16 + ch;
    float acc = 0.f;
    int i0 = off_t[n], i1 = off_t[n + 1];
    for (int i = i0; i < i1; i++) {
        acc += __half2float(ht[(size_t)i * 16]);
    }
    i0 = off_s[n]; i1 = off_s[n + 1];
    for (int i = i0; i < i1; i++) {
        acc -= __half2float(hs[(size_t)i * 16]);
    }
    agg[((size_t)b * NN + n) * 16 + ch] = acc;
}

// ---------------- node: gnn-out + GRU + fc ------------------------------------
__global__ __launch_bounds__(256) void node_kernel(
    float* xnio, const float* __restrict__ feature, int t,
    const float* __restrict__ agg, const float* __restrict__ nb,
    const float* __restrict__ wi, const float* __restrict__ wh,
    const float* __restrict__ bi, const float* __restrict__ bh,
    const float* __restrict__ fw, const float* __restrict__ fb,
    float* __restrict__ hnbuf, float* __restrict__ out)
{
    __shared__ float xpart[4][64];
    int lane = threadIdx.x & 63;
    int wav  = threadIdx.x >> 6;
    int node = blockIdx.x * 64 + lane;
    int b = node / NN;
    int n = node - b * NN;

    float xc[GINC];
    {
        const float4* ar = reinterpret_cast<const float4*>(agg + (size_t)node * 16);
        float4 a0 = ar[0], a1 = ar[1], a2 = ar[2];
        float a3 = agg[(size_t)node * 16 + 12];
        xc[0] = sigm(a0.x + nb[0]);  xc[1] = sigm(a0.y + nb[1]);
        xc[2] = sigm(a0.z + nb[2]);  xc[3] = sigm(a0.w + nb[3]);
        xc[4] = sigm(a1.x + nb[4]);  xc[5] = sigm(a1.y + nb[5]);
        xc[6] = sigm(a1.z + nb[6]);  xc[7] = sigm(a1.w + nb[7]);
        xc[8] = sigm(a2.x + nb[8]);  xc[9] = sigm(a2.y + nb[9]);
        xc[10] = sigm(a2.z + nb[10]); xc[11] = sigm(a2.w + nb[11]);
        xc[12] = sigm(a3 + nb[12]);
    }
    xc[13] = xnio[node];
    {
        const float4* fp = reinterpret_cast<const float4*>(
            feature + (((size_t)b * TSTEP + HISTC + t) * NN + n) * FEX);
        float4 u = fp[0], v = fp[1];
        xc[14] = u.x; xc[15] = u.y; xc[16] = u.z; xc[17] = u.w;
        xc[18] = v.x; xc[19] = v.y; xc[20] = v.z; xc[21] = v.w;
    }

    float h[HIDC];
    #pragma unroll
    for (int k = 0; k < HIDC; k++) h[k] = hnbuf[(size_t)k * BN + node];
    __syncthreads();

    float xsum = 0.f;
    for (int jj = 0; jj < 16; jj++) {
        int j = __builtin_amdgcn_readfirstlane(wav * 16 + jj);  // wave-uniform -> s_load
        float ir = bi[j], iz = bi[64 + j], in_ = bi[128 + j];
        const float* wr0 = wi + (size_t)j * GINC;
        const float* wr1 = wi + (size_t)(64 + j) * GINC;
        const float* wr2 = wi + (size_t)(128 + j) * GINC;
        #pragma unroll
        for (int k = 0; k < GINC; k++) {
            ir  += wr0[k] * xc[k];
            iz  += wr1[k] * xc[k];
            in_ += wr2[k] * xc[k];
        }
        float hr = bh[j], hz = bh[64 + j], hn_ = bh[128 + j];
        const float* vr0 = wh + (size_t)j * HIDC;
        const float* vr1 = wh + (size_t)(64 + j) * HIDC;
        const float* vr2 = wh + (size_t)(128 + j) * HIDC;
        #pragma unroll
        for (int k = 0; k < HIDC; k++) {
            hr  += vr0[k] * h[k];
            hz  += vr1[k] * h[k];
            hn_ += vr2[k] * h[k];
        }
        float r  = sigm(ir + hr);
        float z  = sigm(iz + hz);
        float nn = tanh_fast(in_ + r * hn_);
        float hold = hnbuf[(size_t)j * BN + node];
        float hnew = (1.f - z) * nn + z * hold;
        hnbuf[(size_t)j * BN + node] = hnew;
        xsum += hnew * fw[j];
    }
    xpart[wav][lane] = xsum;
    __syncthreads();
    if (wav == 0) {
        float tot = xpart[0][lane] + xpart[1][lane] + xpart[2][lane] + xpart[3][lane] + fb[0];
        xnio[node] = tot;
        out[(size_t)node * PREDC + t] = tot;
    }
}

extern "C" void kernel_launch(void* const* d_in, const int* in_sizes, int n_in,
                              void* d_out, int out_size, void* d_ws, size_t ws_size,
                              hipStream_t stream)
{
    const float* pm    = (const float*)d_in[0];
    const float* feat  = (const float*)d_in[1];
    const float* ea    = (const float*)d_in[2];
    const float* wmean = (const float*)d_in[3];
    const float* wstd  = (const float*)d_in[4];
    const float* ew1   = (const float*)d_in[5];
    const float* eb1   = (const float*)d_in[6];
    const float* ew2   = (const float*)d_in[7];
    const float* eb2   = (const float*)d_in[8];
    const float* nw    = (const float*)d_in[9];
    const float* nb    = (const float*)d_in[10];
    const float* wi    = (const float*)d_in[11];
    const float* wh    = (const float*)d_in[12];
    const float* bi    = (const float*)d_in[13];
    const float* bh    = (const float*)d_in[14];
    const float* fw    = (const float*)d_in[15];
    const float* fb    = (const float*)d_in[16];
    const int*   eidx  = (const int*)d_in[17];
    float* out = (float*)d_out;

    char* w = (char*)d_ws;
    double* partd = (double*)w;                    w += 256 * 4 * sizeof(double);
    float*  stats = (float*)w;                     w += 16 * sizeof(float);
    float2* epre2 = (float2*)w;                    w += (size_t)EE * sizeof(float2);
    __half* evb   = (__half*)w;                    w += (size_t)EE * EHID * sizeof(__half);
    float*  xn    = (float*)w;                     w += (size_t)BN * sizeof(float);
    float*  hnb   = (float*)w;                     w += (size_t)HIDC * BN * sizeof(float);
    float*  agg13 = (float*)w;                     w += (size_t)BN * 16 * sizeof(float);
    float*  preS  = (float*)w;                     w += (size_t)BN * EHID * sizeof(float);
    float*  preT  = (float*)w;                     w += (size_t)BN * EHID * sizeof(float);
    float2* wind2 = (float2*)w;                    w += (size_t)BN * sizeof(float2);
    __half* h3t   = (__half*)w;                    w += (size_t)BB * EE * 16 * sizeof(__half);
    __half* h3s   = (__half*)w;                    w += (size_t)BB * EE * 16 * sizeof(__half);
    int*    deg_t = (int*)w;                       w += NN * sizeof(int);
    int*    deg_s = (int*)w;                       w += NN * sizeof(int);
    int*    off_t = (int*)w;                       w += (NN + 1) * sizeof(int);
    int*    off_s = (int*)w;                       w += (NN + 1) * sizeof(int);
    int*    cnt_t = (int*)w;                       w += NN * sizeof(int);
    int*    cnt_s = (int*)w;                       w += NN * sizeof(int);
    int*    pos_t = (int*)w;                       w += (size_t)EE * sizeof(int);
    int*    pos_s = (int*)w;                       w += (size_t)EE * sizeof(int);

    stats1_kernel<<<256, 256, 0, stream>>>(ea, partd);
    stats2_kernel<<<1, 256, 0, stream>>>(partd, stats);
    edgepre_kernel<<<(EE + 255) / 256, 256, 0, stream>>>(ea, stats, ew1, eb1, epre2, evb);
    initxn_kernel<<<(BN + 255) / 256, 256, 0, stream>>>(pm, xn);
    hipMemsetAsync(hnb, 0, (size_t)HIDC * BN * sizeof(float), stream);
    hipMemsetAsync(deg_t, 0, 2 * NN * sizeof(int), stream);
    hist_kernel<<<(EE + 255) / 256, 256, 0, stream>>>(eidx, deg_t, deg_s);
    scan_kernel<<<1, 1024, 0, stream>>>(deg_t, deg_s, off_t, off_s, cnt_t, cnt_s);
    fill_kernel<<<(EE + 255) / 256, 256, 0, stream>>>(eidx, cnt_t, cnt_s, pos_t, pos_s);

    for (int t = 0; t < PREDC; t++) {
        pre_kernel<<<(BN + 255) / 256, 256, 0, stream>>>(
            xn, feat, t, ew1, wmean, wstd, preS, preT, wind2);
        edge_kernel<<<dim3((EE + 255) / 256, 2), 256, 0, stream>>>(
            eidx, epre2, evb, preS, preT, wind2, pos_t, pos_s,
            ew1, ew2, eb2, nw, h3t, h3s);
        gather_kernel<<<(NN * 64 + 255) / 256, 256, 0, stream>>>(
            h3t, h3s, off_t, off_s, agg13);
        node_kernel<<<BN / 64, 256, 0, stream>>>(
            xn, feat, t, agg13, nb, wi, wh, bi, bh, fw, fb, hnb, out);
    }
}

// Round 5
// 2021.814 us; speedup vs baseline: 1.1384x; 1.1384x over previous
//
#include <hip/hip_runtime.h>
#include <hip/hip_fp16.h>
#include <cstddef>

#define BB    4
#define NN    10000
#define EE    160000
#define BN    40000      // BB*NN
#define HISTC 8
#define PREDC 12
#define TSTEP 20         // HIST+PRED
#define FEX   8
#define HIDC  64
#define EHID  32
#define EOUTC 30
#define GOUTC 13
#define GINC  22         // GOUTC + 9

typedef float v2f __attribute__((ext_vector_type(2)));

__device__ __forceinline__ float fast_rcp(float x) { return __builtin_amdgcn_rcpf(x); }
__device__ __forceinline__ float sigm(float x) {
    return fast_rcp(1.0f + __expf(-x));
}
__device__ __forceinline__ v2f sigm2(v2f x) {
    v2f r; r.x = sigm(x.x); r.y = sigm(x.y); return r;
}
__device__ __forceinline__ float tanh_fast(float x) {
    x = fminf(fmaxf(x, -15.0f), 15.0f);
    float e = __expf(2.0f * x);
    return (e - 1.0f) * fast_rcp(e + 1.0f);
}

// ---------------- edge_attr stats: stage 1 (per-block partials) ---------------
__global__ __launch_bounds__(256) void stats1_kernel(const float* __restrict__ ea,
                                                     double* __restrict__ part) {
    __shared__ double sm[256][4];
    int tid = threadIdx.x;
    double s0 = 0, s1 = 0, q0 = 0, q1 = 0;
    for (int e = blockIdx.x * 256 + tid; e < EE; e += 256 * 256) {
        float2 v = reinterpret_cast<const float2*>(ea)[e];
        double v0 = (double)v.x, v1 = (double)v.y;
        s0 += v0; q0 += v0 * v0;
        s1 += v1; q1 += v1 * v1;
    }
    sm[tid][0] = s0; sm[tid][1] = s1; sm[tid][2] = q0; sm[tid][3] = q1;
    __syncthreads();
    for (int off = 128; off > 0; off >>= 1) {
        if (tid < off)
            for (int k = 0; k < 4; k++) sm[tid][k] += sm[tid + off][k];
        __syncthreads();
    }
    if (tid == 0) {
        part[blockIdx.x * 4 + 0] = sm[0][0];
        part[blockIdx.x * 4 + 1] = sm[0][1];
        part[blockIdx.x * 4 + 2] = sm[0][2];
        part[blockIdx.x * 4 + 3] = sm[0][3];
    }
}

__global__ __launch_bounds__(256) void stats2_kernel(const double* __restrict__ part,
                                                     float* __restrict__ stats) {
    __shared__ double sm[256][4];
    int tid = threadIdx.x;
    sm[tid][0] = part[tid * 4 + 0];
    sm[tid][1] = part[tid * 4 + 1];
    sm[tid][2] = part[tid * 4 + 2];
    sm[tid][3] = part[tid * 4 + 3];
    __syncthreads();
    for (int off = 128; off > 0; off >>= 1) {
        if (tid < off)
            for (int k = 0; k < 4; k++) sm[tid][k] += sm[tid + off][k];
        __syncthreads();
    }
    if (tid == 0) {
        double m0 = sm[0][0] / EE, m1 = sm[0][1] / EE;
        double v0 = (sm[0][2] - sm[0][0] * sm[0][0] / EE) / (double)(EE - 1);
        double v1 = (sm[0][3] - sm[0][1] * sm[0][1] / EE) / (double)(EE - 1);
        float sd0 = fmaxf((float)sqrt(v0 > 0 ? v0 : 0.0), 1e-6f);
        float sd1 = fmaxf((float)sqrt(v1 > 0 ? v1 : 0.0), 1e-6f);
        stats[0] = (float)m0; stats[1] = (float)m1;
        stats[2] = 1.0f / sd0; stats[3] = 1.0f / sd1;
    }
}

// ---------------- per-edge precompute: epre4 = {ean0, ean1, 1/dist, direc} ----
__global__ __launch_bounds__(256) void edgepre_kernel(
    const float* __restrict__ ea, const float* __restrict__ stats,
    float4* __restrict__ epre4)
{
    int e = blockIdx.x * 256 + threadIdx.x;
    if (e >= EE) return;
    float2 v = reinterpret_cast<const float2*>(ea)[e];
    float4 r;
    r.x = (v.x - stats[0]) * stats[2];
    r.y = (v.y - stats[1]) * stats[3];
    r.z = 1.0f / fmaxf(v.x, 1e-3f);
    r.w = v.y;
    epre4[e] = r;
}

// ---------------- xn init from pm25_hist[:, -1] -------------------------------
__global__ void initxn_kernel(const float* __restrict__ pm, float* __restrict__ xn) {
    int i = blockIdx.x * 256 + threadIdx.x;
    if (i >= BN) return;
    int b = i / NN, n = i - b * NN;
    xn[i] = pm[(b * HISTC + (HISTC - 1)) * NN + n];
}

// ---------------- CSR build (once per call) -----------------------------------
__global__ void hist_kernel(const int* __restrict__ eidx,
                            int* __restrict__ deg_t, int* __restrict__ deg_s) {
    int e = blockIdx.x * 256 + threadIdx.x;
    if (e >= EE) return;
    atomicAdd(&deg_s[eidx[e]], 1);
    atomicAdd(&deg_t[eidx[EE + e]], 1);
}

__global__ __launch_bounds__(1024) void scan_kernel(
    const int* __restrict__ deg_t, const int* __restrict__ deg_s,
    int* __restrict__ off_t, int* __restrict__ off_s,
    int* __restrict__ cnt_t, int* __restrict__ cnt_s)
{
    __shared__ int pt[1024], ps[1024];
    int tid = threadIdx.x;
    int base = tid * 10;
    int st = 0, ss = 0;
    for (int k = 0; k < 10; k++) {
        int i = base + k;
        if (i < NN) { st += deg_t[i]; ss += deg_s[i]; }
    }
    pt[tid] = st; ps[tid] = ss;
    __syncthreads();
    for (int off = 1; off < 1024; off <<= 1) {
        int vt = (tid >= off) ? pt[tid - off] : 0;
        int vs = (tid >= off) ? ps[tid - off] : 0;
        __syncthreads();
        pt[tid] += vt; ps[tid] += vs;
        __syncthreads();
    }
    int ext = (tid == 0) ? 0 : pt[tid - 1];
    int exs = (tid == 0) ? 0 : ps[tid - 1];
    for (int k = 0; k < 10; k++) {
        int i = base + k;
        if (i < NN) {
            off_t[i] = ext; cnt_t[i] = ext;
            off_s[i] = exs; cnt_s[i] = exs;
            ext += deg_t[i]; exs += deg_s[i];
        }
    }
    if (tid == 0) { off_t[NN] = EE; off_s[NN] = EE; }
}

__global__ void fill_kernel(const int* __restrict__ eidx,
                            int* __restrict__ cnt_t, int* __restrict__ cnt_s,
                            int* __restrict__ pos_t, int* __restrict__ pos_s)
{
    int e = blockIdx.x * 256 + threadIdx.x;
    if (e >= EE) return;
    int s = eidx[e];
    int g = eidx[EE + e];
    pos_t[e] = atomicAdd(&cnt_t[g], 1);
    pos_s[e] = atomicAdd(&cnt_s[s], 1);
}

// ---------------- per-step node precompute (fp16 tables) ----------------------
// 8 threads per node; thread (i, c) computes outputs o in [4c, 4c+4) of
// preS[i][o] = sum_k x[k]*W1[k][o], preT[i][o] = sum_k x[k]*W1[9+k][o]
// stored fp16, row = 32 halves (64 B). Coalesced 8 B stores.
__global__ __launch_bounds__(256) void pre_kernel(
    const float* __restrict__ xn, const float* __restrict__ feature, int t,
    const float* __restrict__ ew1,
    const float* __restrict__ wmean, const float* __restrict__ wstd,
    __half* __restrict__ preS, __half* __restrict__ preT, float2* __restrict__ wind2)
{
    __shared__ alignas(16) float w1s[18 * EHID];
    for (int i = threadIdx.x; i < 18 * EHID; i += 256) w1s[i] = ew1[i];
    __syncthreads();
    int idx = blockIdx.x * 256 + threadIdx.x;
    if (idx >= BN * 8) return;
    int i = idx >> 3;
    int c = idx & 7;
    int b = i / NN, n = i - b * NN;
    float x[9];
    x[0] = xn[i];
    {
        const float4* fp = reinterpret_cast<const float4*>(
            feature + (((size_t)b * TSTEP + HISTC + t) * NN + n) * FEX);
        float4 u = fp[0], v = fp[1];
        x[1] = u.x; x[2] = u.y; x[3] = u.z; x[4] = u.w;
        x[5] = v.x; x[6] = v.y; x[7] = v.z; x[8] = v.w;
    }
    float4 aS = {0.f, 0.f, 0.f, 0.f}, aT = {0.f, 0.f, 0.f, 0.f};
    #pragma unroll
    for (int k = 0; k < 9; k++) {
        float4 wS = reinterpret_cast<const float4*>(&w1s[k * EHID])[c];
        float4 wT = reinterpret_cast<const float4*>(&w1s[(9 + k) * EHID])[c];
        aS.x += x[k] * wS.x; aS.y += x[k] * wS.y; aS.z += x[k] * wS.z; aS.w += x[k] * wS.w;
        aT.x += x[k] * wT.x; aT.y += x[k] * wT.y; aT.z += x[k] * wT.z; aT.w += x[k] * wT.w;
    }
    union { uint2 u; __half h[4]; } sv, tv;
    sv.h[0] = __float2half(aS.x); sv.h[1] = __float2half(aS.y);
    sv.h[2] = __float2half(aS.z); sv.h[3] = __float2half(aS.w);
    tv.h[0] = __float2half(aT.x); tv.h[1] = __float2half(aT.y);
    tv.h[2] = __float2half(aT.z); tv.h[3] = __float2half(aT.w);
    reinterpret_cast<uint2*>(preS + (size_t)i * EHID)[c] = sv.u;
    reinterpret_cast<uint2*>(preT + (size_t)i * EHID)[c] = tv.u;
    if (c == 0) {
        float sd0 = fmaxf(wstd[0], 1e-6f), sd1 = fmaxf(wstd[1], 1e-6f);
        float speed = fmaxf(x[7] * sd0 + wmean[0], 0.f);
        float wdir  = (x[8] * sd1 + wmean[1]) * 0.017453292519943295f;
        float2 wv; wv.x = 3.0f * speed; wv.y = wdir;
        wind2[i] = wv;
    }
}

// ---------------- edge MLP (layers 2,3 + folded n_w) --------------------------
// grid (EE/256, 2); blockIdx.y = bA; thread handles batches bA and bA+2 via
// packed float2. Layer 1 = fp16 table adds + inline ev recompute from LDS.
__global__ __launch_bounds__(256) void edge_kernel(
    const int* __restrict__ eidx, const float4* __restrict__ epre4,
    const __half* __restrict__ preS, const __half* __restrict__ preT,
    const float2* __restrict__ wind2,
    const int* __restrict__ pos_t, const int* __restrict__ pos_s,
    const float* __restrict__ ew1, const float* __restrict__ eb1,
    const float* __restrict__ ew2, const float* __restrict__ eb2,
    const float* __restrict__ nw,
    __half* __restrict__ h3t, __half* __restrict__ h3s)
{
    __shared__ alignas(16) float w2t[EOUTC * EHID];    // [o][k]
    __shared__ alignas(16) float nws16[EOUTC * 16];    // [o][j] padded
    __shared__ alignas(16) float w18[EHID], w19[EHID], w20[EHID], b1s[EHID];
    __shared__ float b2s[EOUTC];
    for (int i = threadIdx.x; i < EOUTC * EHID; i += 256) {
        int o = i / EHID, k = i - o * EHID;
        w2t[i] = ew2[k * EOUTC + o];
    }
    for (int i = threadIdx.x; i < EOUTC * 16; i += 256) {
        int o = i >> 4, j = i & 15;
        nws16[i] = (j < GOUTC) ? nw[o * GOUTC + j] : 0.f;
    }
    if (threadIdx.x < EHID) {
        w18[threadIdx.x] = ew1[18 * EHID + threadIdx.x];
        w19[threadIdx.x] = ew1[19 * EHID + threadIdx.x];
        w20[threadIdx.x] = ew1[20 * EHID + threadIdx.x];
        b1s[threadIdx.x] = eb1[threadIdx.x];
    }
    if (threadIdx.x < EOUTC) b2s[threadIdx.x] = eb2[threadIdx.x];
    __syncthreads();

    int e = blockIdx.x * 256 + threadIdx.x;
    if (e >= EE) return;
    int bA = blockIdx.y;
    int bB = bA + 2;
    int s = eidx[e];
    int g = eidx[EE + e];
    int pt = pos_t[e];
    int ps = pos_s[e];
    float4 ep = epre4[e];          // {ean0, ean1, 1/dist, direc}

    size_t iSA = (size_t)bA * NN + s, iTA = (size_t)bA * NN + g;
    size_t iSB = (size_t)bB * NN + s, iTB = (size_t)bB * NN + g;
    float2 wA = wind2[iSA];
    float2 wB = wind2[iSB];
    v2f ew;
    ew.x = fmaxf(wA.x * __cosf(fabsf(ep.w - wA.y)) * ep.z, 0.f);
    ew.y = fmaxf(wB.x * __cosf(fabsf(ep.w - wB.y)) * ep.z, 0.f);

    // gather four fp16 rows (64 B each)
    union alignas(16) { uint4 u[4]; __half h[EHID]; } RSA, RTA, RSB, RTB;
    {
        const uint4* p;
        p = reinterpret_cast<const uint4*>(preS + iSA * EHID);
        RSA.u[0] = p[0]; RSA.u[1] = p[1]; RSA.u[2] = p[2]; RSA.u[3] = p[3];
        p = reinterpret_cast<const uint4*>(preT + iTA * EHID);
        RTA.u[0] = p[0]; RTA.u[1] = p[1]; RTA.u[2] = p[2]; RTA.u[3] = p[3];
        p = reinterpret_cast<const uint4*>(preS + iSB * EHID);
        RSB.u[0] = p[0]; RSB.u[1] = p[1]; RSB.u[2] = p[2]; RSB.u[3] = p[3];
        p = reinterpret_cast<const uint4*>(preT + iTB * EHID);
        RTB.u[0] = p[0]; RTB.u[1] = p[1]; RTB.u[2] = p[2]; RTB.u[3] = p[3];
    }

    float ean0 = ep.x, ean1 = ep.y;
    v2f h1v[EHID];
    #pragma unroll
    for (int q = 0; q < 8; q++) {
        float4 w18q = reinterpret_cast<const float4*>(w18)[q];
        float4 w19q = reinterpret_cast<const float4*>(w19)[q];
        float4 b1q  = reinterpret_cast<const float4*>(b1s)[q];
        float4 w20q = reinterpret_cast<const float4*>(w20)[q];
        float ev0 = ean0 * w18q.x + ean1 * w19q.x + b1q.x;
        float ev1 = ean0 * w18q.y + ean1 * w19q.y + b1q.y;
        float ev2 = ean0 * w18q.z + ean1 * w19q.z + b1q.z;
        float ev3 = ean0 * w18q.w + ean1 * w19q.w + b1q.w;
        v2f u;
        u.x = __half2float(RSA.h[4*q+0]) + __half2float(RTA.h[4*q+0]) + ev0;
        u.y = __half2float(RSB.h[4*q+0]) + __half2float(RTB.h[4*q+0]) + ev0;
        u += w20q.x * ew; h1v[4*q+0] = sigm2(u);
        u.x = __half2float(RSA.h[4*q+1]) + __half2float(RTA.h[4*q+1]) + ev1;
        u.y = __half2float(RSB.h[4*q+1]) + __half2float(RTB.h[4*q+1]) + ev1;
        u += w20q.y * ew; h1v[4*q+1] = sigm2(u);
        u.x = __half2float(RSA.h[4*q+2]) + __half2float(RTA.h[4*q+2]) + ev2;
        u.y = __half2float(RSB.h[4*q+2]) + __half2float(RTB.h[4*q+2]) + ev2;
        u += w20q.z * ew; h1v[4*q+2] = sigm2(u);
        u.x = __half2float(RSA.h[4*q+3]) + __half2float(RTA.h[4*q+3]) + ev3;
        u.y = __half2float(RSB.h[4*q+3]) + __half2float(RTB.h[4*q+3]) + ev3;
        u += w20q.w * ew; h1v[4*q+3] = sigm2(u);
    }

    v2f h3v[GOUTC];
    #pragma unroll
    for (int j = 0; j < GOUTC; j++) { h3v[j].x = 0.f; h3v[j].y = 0.f; }

    for (int o = 0; o < EOUTC; o++) {
        v2f acc; acc.x = b2s[o]; acc.y = b2s[o];
        const float4* wr = reinterpret_cast<const float4*>(&w2t[o * EHID]);
        #pragma unroll
        for (int q = 0; q < 8; q++) {
            float4 wq = wr[q];
            acc += wq.x * h1v[4*q+0];
            acc += wq.y * h1v[4*q+1];
            acc += wq.z * h1v[4*q+2];
            acc += wq.w * h1v[4*q+3];
        }
        v2f h2 = sigm2(acc);
        const float4* nr = reinterpret_cast<const float4*>(&nws16[o * 16]);
        float4 n0 = nr[0], n1 = nr[1], n2 = nr[2], n3 = nr[3];
        h3v[0]  += n0.x * h2;  h3v[1]  += n0.y * h2;
        h3v[2]  += n0.z * h2;  h3v[3]  += n0.w * h2;
        h3v[4]  += n1.x * h2;  h3v[5]  += n1.y * h2;
        h3v[6]  += n1.z * h2;  h3v[7]  += n1.w * h2;
        h3v[8]  += n2.x * h2;  h3v[9]  += n2.y * h2;
        h3v[10] += n2.z * h2;  h3v[11] += n2.w * h2;
        h3v[12] += n3.x * h2;
    }

    alignas(16) __half rA[16], rB[16];
    #pragma unroll
    for (int j = 0; j < GOUTC; j++) {
        rA[j] = __float2half(h3v[j].x);
        rB[j] = __float2half(h3v[j].y);
    }
    #pragma unroll
    for (int j = GOUTC; j < 16; j++) { rA[j] = __float2half(0.f); rB[j] = __float2half(0.f); }
    uint4 rA0 = reinterpret_cast<const uint4*>(rA)[0];
    uint4 rA1 = reinterpret_cast<const uint4*>(rA)[1];
    uint4 rB0 = reinterpret_cast<const uint4*>(rB)[0];
    uint4 rB1 = reinterpret_cast<const uint4*>(rB)[1];
    {
        __half* oA = h3t + ((size_t)bA * EE + pt) * 16;
        __half* oB = h3t + ((size_t)bB * EE + pt) * 16;
        reinterpret_cast<uint4*>(oA)[0] = rA0;
        reinterpret_cast<uint4*>(oA)[1] = rA1;
        reinterpret_cast<uint4*>(oB)[0] = rB0;
        reinterpret_cast<uint4*>(oB)[1] = rB1;
    }
    {
        __half* oA = h3s + ((size_t)bA * EE + ps) * 16;
        __half* oB = h3s + ((size_t)bB * EE + ps) * 16;
        reinterpret_cast<uint4*>(oA)[0] = rA0;
        reinterpret_cast<uint4*>(oA)[1] = rA1;
        reinterpret_cast<uint4*>(oB)[0] = rB0;
        reinterpret_cast<uint4*>(oB)[1] = rB1;
    }
}

// ---------------- gather: agg13[b][n][ch] = sum_in h3t - sum_out h3s ----------
__global__ __launch_bounds__(256) void gather_kernel(
    const __half* __restrict__ h3t, const __half* __restrict__ h3s,
    const int* __restrict__ off_t, const int* __restrict__ off_s,
    float* __restrict__ agg)
{
    int n = (blockIdx.x * 256 + threadIdx.x) >> 6;
    if (n >= NN) return;
    n = __builtin_amdgcn_readfirstlane(n);
    int lane = threadIdx.x & 63;
    int b = lane >> 4, ch = lane & 15;
    const __half* ht = h3t + (size_t)b * EE * 16 + ch;
    const __half* hs = h3s + (size_t)b * EE * 16 + ch;
    float acc = 0.f;
    int i0 = off_t[n], i1 = off_t[n + 1];
    for (int i = i0; i < i1; i++) {
        acc += __half2float(ht[(size_t)i * 16]);
    }
    i0 = off_s[n]; i1 = off_s[n + 1];
    for (int i = i0; i < i1; i++) {
        acc -= __half2float(hs[(size_t)i * 16]);
    }
    agg[((size_t)b * NN + n) * 16 + ch] = acc;
}

// ---------------- node: gnn-out + GRU + fc ------------------------------------
__global__ __launch_bounds__(256) void node_kernel(
    float* xnio, const float* __restrict__ feature, int t,
    const float* __restrict__ agg, const float* __restrict__ nb,
    const float* __restrict__ wi, const float* __restrict__ wh,
    const float* __restrict__ bi, const float* __restrict__ bh,
    const float* __restrict__ fw, const float* __restrict__ fb,
    float* __restrict__ hnbuf, float* __restrict__ out)
{
    __shared__ float xpart[4][64];
    int lane = threadIdx.x & 63;
    int wav  = threadIdx.x >> 6;
    int node = blockIdx.x * 64 + lane;
    int b = node / NN;
    int n = node - b * NN;

    float xc[GINC];
    {
        const float4* ar = reinterpret_cast<const float4*>(agg + (size_t)node * 16);
        float4 a0 = ar[0], a1 = ar[1], a2 = ar[2];
        float a3 = agg[(size_t)node * 16 + 12];
        xc[0] = sigm(a0.x + nb[0]);  xc[1] = sigm(a0.y + nb[1]);
        xc[2] = sigm(a0.z + nb[2]);  xc[3] = sigm(a0.w + nb[3]);
        xc[4] = sigm(a1.x + nb[4]);  xc[5] = sigm(a1.y + nb[5]);
        xc[6] = sigm(a1.z + nb[6]);  xc[7] = sigm(a1.w + nb[7]);
        xc[8] = sigm(a2.x + nb[8]);  xc[9] = sigm(a2.y + nb[9]);
        xc[10] = sigm(a2.z + nb[10]); xc[11] = sigm(a2.w + nb[11]);
        xc[12] = sigm(a3 + nb[12]);
    }
    xc[13] = xnio[node];
    {
        const float4* fp = reinterpret_cast<const float4*>(
            feature + (((size_t)b * TSTEP + HISTC + t) * NN + n) * FEX);
        float4 u = fp[0], v = fp[1];
        xc[14] = u.x; xc[15] = u.y; xc[16] = u.z; xc[17] = u.w;
        xc[18] = v.x; xc[19] = v.y; xc[20] = v.z; xc[21] = v.w;
    }

    float h[HIDC];
    #pragma unroll
    for (int k = 0; k < HIDC; k++) h[k] = hnbuf[(size_t)k * BN + node];
    __syncthreads();

    float xsum = 0.f;
    for (int jj = 0; jj < 16; jj++) {
        int j = __builtin_amdgcn_readfirstlane(wav * 16 + jj);  // wave-uniform -> s_load
        float ir = bi[j], iz = bi[64 + j], in_ = bi[128 + j];
        const float* wr0 = wi + (size_t)j * GINC;
        const float* wr1 = wi + (size_t)(64 + j) * GINC;
        const float* wr2 = wi + (size_t)(128 + j) * GINC;
        #pragma unroll
        for (int k = 0; k < GINC; k++) {
            ir  += wr0[k] * xc[k];
            iz  += wr1[k] * xc[k];
            in_ += wr2[k] * xc[k];
        }
        float hr = bh[j], hz = bh[64 + j], hn_ = bh[128 + j];
        const float* vr0 = wh + (size_t)j * HIDC;
        const float* vr1 = wh + (size_t)(64 + j) * HIDC;
        const float* vr2 = wh + (size_t)(128 + j) * HIDC;
        #pragma unroll
        for (int k = 0; k < HIDC; k++) {
            hr  += vr0[k] * h[k];
            hz  += vr1[k] * h[k];
            hn_ += vr2[k] * h[k];
        }
        float r  = sigm(ir + hr);
        float z  = sigm(iz + hz);
        float nn = tanh_fast(in_ + r * hn_);
        float hold = hnbuf[(size_t)j * BN + node];
        float hnew = (1.f - z) * nn + z * hold;
        hnbuf[(size_t)j * BN + node] = hnew;
        xsum += hnew * fw[j];
    }
    xpart[wav][lane] = xsum;
    __syncthreads();
    if (wav == 0) {
        float tot = xpart[0][lane] + xpart[1][lane] + xpart[2][lane] + xpart[3][lane] + fb[0];
        xnio[node] = tot;
        out[(size_t)node * PREDC + t] = tot;
    }
}

extern "C" void kernel_launch(void* const* d_in, const int* in_sizes, int n_in,
                              void* d_out, int out_size, void* d_ws, size_t ws_size,
                              hipStream_t stream)
{
    const float* pm    = (const float*)d_in[0];
    const float* feat  = (const float*)d_in[1];
    const float* ea    = (const float*)d_in[2];
    const float* wmean = (const float*)d_in[3];
    const float* wstd  = (const float*)d_in[4];
    const float* ew1   = (const float*)d_in[5];
    const float* eb1   = (const float*)d_in[6];
    const float* ew2   = (const float*)d_in[7];
    const float* eb2   = (const float*)d_in[8];
    const float* nw    = (const float*)d_in[9];
    const float* nb    = (const float*)d_in[10];
    const float* wi    = (const float*)d_in[11];
    const float* wh    = (const float*)d_in[12];
    const float* bi    = (const float*)d_in[13];
    const float* bh    = (const float*)d_in[14];
    const float* fw    = (const float*)d_in[15];
    const float* fb    = (const float*)d_in[16];
    const int*   eidx  = (const int*)d_in[17];
    float* out = (float*)d_out;

    char* w = (char*)d_ws;
    double* partd = (double*)w;                    w += 256 * 4 * sizeof(double);
    float*  stats = (float*)w;                     w += 16 * sizeof(float);
    float4* epre4 = (float4*)w;                    w += (size_t)EE * sizeof(float4);
    float*  xn    = (float*)w;                     w += (size_t)BN * sizeof(float);
    float*  hnb   = (float*)w;                     w += (size_t)HIDC * BN * sizeof(float);
    float*  agg13 = (float*)w;                     w += (size_t)BN * 16 * sizeof(float);
    __half* preS  = (__half*)w;                    w += (size_t)BN * EHID * sizeof(__half);
    __half* preT  = (__half*)w;                    w += (size_t)BN * EHID * sizeof(__half);
    float2* wind2 = (float2*)w;                    w += (size_t)BN * sizeof(float2);
    __half* h3t   = (__half*)w;                    w += (size_t)BB * EE * 16 * sizeof(__half);
    __half* h3s   = (__half*)w;                    w += (size_t)BB * EE * 16 * sizeof(__half);
    int*    deg_t = (int*)w;                       w += NN * sizeof(int);
    int*    deg_s = (int*)w;                       w += NN * sizeof(int);
    int*    off_t = (int*)w;                       w += (NN + 1) * sizeof(int);
    int*    off_s = (int*)w;                       w += (NN + 1) * sizeof(int);
    int*    cnt_t = (int*)w;                       w += NN * sizeof(int);
    int*    cnt_s = (int*)w;                       w += NN * sizeof(int);
    int*    pos_t = (int*)w;                       w += (size_t)EE * sizeof(int);
    int*    pos_s = (int*)w;                       w += (size_t)EE * sizeof(int);

    stats1_kernel<<<256, 256, 0, stream>>>(ea, partd);
    stats2_kernel<<<1, 256, 0, stream>>>(partd, stats);
    edgepre_kernel<<<(EE + 255) / 256, 256, 0, stream>>>(ea, stats, epre4);
    initxn_kernel<<<(BN + 255) / 256, 256, 0, stream>>>(pm, xn);
    hipMemsetAsync(hnb, 0, (size_t)HIDC * BN * sizeof(float), stream);
    hipMemsetAsync(deg_t, 0, 2 * NN * sizeof(int), stream);
    hist_kernel<<<(EE + 255) / 256, 256, 0, stream>>>(eidx, deg_t, deg_s);
    scan_kernel<<<1, 1024, 0, stream>>>(deg_t, deg_s, off_t, off_s, cnt_t, cnt_s);
    fill_kernel<<<(EE + 255) / 256, 256, 0, stream>>>(eidx, cnt_t, cnt_s, pos_t, pos_s);

    for (int t = 0; t < PREDC; t++) {
        pre_kernel<<<(BN * 8 + 255) / 256, 256, 0, stream>>>(
            xn, feat, t, ew1, wmean, wstd, preS, preT, wind2);
        edge_kernel<<<dim3((EE + 255) / 256, 2), 256, 0, stream>>>(
            eidx, epre4, preS, preT, wind2, pos_t, pos_s,
            ew1, eb1, ew2, eb2, nw, h3t, h3s);
        gather_kernel<<<(NN * 64 + 255) / 256, 256, 0, stream>>>(
            h3t, h3s, off_t, off_s, agg13);
        node_kernel<<<BN / 64, 256, 0, stream>>>(
            xn, feat, t, agg13, nb, wi, wh, bi, bh, fw, fb, hnb, out);
    }
}

// Round 6
// 1732.746 us; speedup vs baseline: 1.3283x; 1.1668x over previous
//
#include <hip/hip_runtime.h>
#include <hip/hip_fp16.h>
#include <cstddef>

#define BB    4
#define NN    10000
#define EE    160000
#define BN    40000      // BB*NN
#define HISTC 8
#define PREDC 12
#define TSTEP 20         // HIST+PRED
#define FEX   8
#define HIDC  64
#define EHID  32
#define EOUTC 30
#define GOUTC 13
#define GINC  22         // GOUTC + 9

__device__ __forceinline__ float fast_rcp(float x) { return __builtin_amdgcn_rcpf(x); }
__device__ __forceinline__ float sigm(float x) {
    return fast_rcp(1.0f + __expf(-x));
}
__device__ __forceinline__ float tanh_fast(float x) {
    x = fminf(fmaxf(x, -15.0f), 15.0f);
    float e = __expf(2.0f * x);
    return (e - 1.0f) * fast_rcp(e + 1.0f);
}

// ---------------- edge_attr stats: stage 1 (per-block partials) ---------------
__global__ __launch_bounds__(256) void stats1_kernel(const float* __restrict__ ea,
                                                     double* __restrict__ part) {
    __shared__ double sm[256][4];
    int tid = threadIdx.x;
    double s0 = 0, s1 = 0, q0 = 0, q1 = 0;
    for (int e = blockIdx.x * 256 + tid; e < EE; e += 256 * 256) {
        float2 v = reinterpret_cast<const float2*>(ea)[e];
        double v0 = (double)v.x, v1 = (double)v.y;
        s0 += v0; q0 += v0 * v0;
        s1 += v1; q1 += v1 * v1;
    }
    sm[tid][0] = s0; sm[tid][1] = s1; sm[tid][2] = q0; sm[tid][3] = q1;
    __syncthreads();
    for (int off = 128; off > 0; off >>= 1) {
        if (tid < off)
            for (int k = 0; k < 4; k++) sm[tid][k] += sm[tid + off][k];
        __syncthreads();
    }
    if (tid == 0) {
        part[blockIdx.x * 4 + 0] = sm[0][0];
        part[blockIdx.x * 4 + 1] = sm[0][1];
        part[blockIdx.x * 4 + 2] = sm[0][2];
        part[blockIdx.x * 4 + 3] = sm[0][3];
    }
}

__global__ __launch_bounds__(256) void stats2_kernel(const double* __restrict__ part,
                                                     float* __restrict__ stats) {
    __shared__ double sm[256][4];
    int tid = threadIdx.x;
    sm[tid][0] = part[tid * 4 + 0];
    sm[tid][1] = part[tid * 4 + 1];
    sm[tid][2] = part[tid * 4 + 2];
    sm[tid][3] = part[tid * 4 + 3];
    __syncthreads();
    for (int off = 128; off > 0; off >>= 1) {
        if (tid < off)
            for (int k = 0; k < 4; k++) sm[tid][k] += sm[tid + off][k];
        __syncthreads();
    }
    if (tid == 0) {
        double m0 = sm[0][0] / EE, m1 = sm[0][1] / EE;
        double v0 = (sm[0][2] - sm[0][0] * sm[0][0] / EE) / (double)(EE - 1);
        double v1 = (sm[0][3] - sm[0][1] * sm[0][1] / EE) / (double)(EE - 1);
        float sd0 = fmaxf((float)sqrt(v0 > 0 ? v0 : 0.0), 1e-6f);
        float sd1 = fmaxf((float)sqrt(v1 > 0 ? v1 : 0.0), 1e-6f);
        stats[0] = (float)m0; stats[1] = (float)m1;
        stats[2] = 1.0f / sd0; stats[3] = 1.0f / sd1;
    }
}

// ---------------- per-edge precompute: epre4 = {ean0, ean1, 1/dist, direc} ----
__global__ __launch_bounds__(256) void edgepre_kernel(
    const float* __restrict__ ea, const float* __restrict__ stats,
    float4* __restrict__ epre4)
{
    int e = blockIdx.x * 256 + threadIdx.x;
    if (e >= EE) return;
    float2 v = reinterpret_cast<const float2*>(ea)[e];
    float4 r;
    r.x = (v.x - stats[0]) * stats[2];
    r.y = (v.y - stats[1]) * stats[3];
    r.z = 1.0f / fmaxf(v.x, 1e-3f);
    r.w = v.y;
    epre4[e] = r;
}

// ---------------- xn init from pm25_hist[:, -1] -------------------------------
__global__ void initxn_kernel(const float* __restrict__ pm, float* __restrict__ xn) {
    int i = blockIdx.x * 256 + threadIdx.x;
    if (i >= BN) return;
    int b = i / NN, n = i - b * NN;
    xn[i] = pm[(b * HISTC + (HISTC - 1)) * NN + n];
}

// ---------------- CSR build (once per call) -----------------------------------
__global__ void hist_kernel(const int* __restrict__ eidx,
                            int* __restrict__ deg_t, int* __restrict__ deg_s) {
    int e = blockIdx.x * 256 + threadIdx.x;
    if (e >= EE) return;
    atomicAdd(&deg_s[eidx[e]], 1);
    atomicAdd(&deg_t[eidx[EE + e]], 1);
}

__global__ __launch_bounds__(1024) void scan_kernel(
    const int* __restrict__ deg_t, const int* __restrict__ deg_s,
    int* __restrict__ off_t, int* __restrict__ off_s,
    int* __restrict__ cnt_t, int* __restrict__ cnt_s)
{
    __shared__ int pt[1024], ps[1024];
    int tid = threadIdx.x;
    int base = tid * 10;
    int st = 0, ss = 0;
    for (int k = 0; k < 10; k++) {
        int i = base + k;
        if (i < NN) { st += deg_t[i]; ss += deg_s[i]; }
    }
    pt[tid] = st; ps[tid] = ss;
    __syncthreads();
    for (int off = 1; off < 1024; off <<= 1) {
        int vt = (tid >= off) ? pt[tid - off] : 0;
        int vs = (tid >= off) ? ps[tid - off] : 0;
        __syncthreads();
        pt[tid] += vt; ps[tid] += vs;
        __syncthreads();
    }
    int ext = (tid == 0) ? 0 : pt[tid - 1];
    int exs = (tid == 0) ? 0 : ps[tid - 1];
    for (int k = 0; k < 10; k++) {
        int i = base + k;
        if (i < NN) {
            off_t[i] = ext; cnt_t[i] = ext;
            off_s[i] = exs; cnt_s[i] = exs;
            ext += deg_t[i]; exs += deg_s[i];
        }
    }
    if (tid == 0) { off_t[NN] = EE; off_s[NN] = EE; }
}

__global__ void fill_kernel(const int* __restrict__ eidx,
                            int* __restrict__ cnt_t, int* __restrict__ cnt_s,
                            int* __restrict__ pos_t, int* __restrict__ pos_s)
{
    int e = blockIdx.x * 256 + threadIdx.x;
    if (e >= EE) return;
    int s = eidx[e];
    int g = eidx[EE + e];
    pos_t[e] = atomicAdd(&cnt_t[g], 1);
    pos_s[e] = atomicAdd(&cnt_s[s], 1);
}

// ---------------- per-step node precompute (fp16 tables) + xn/out finalize ----
// 8 threads per node. Also finalizes previous step's xn total from the two
// j-partials and writes out[t-1].
__global__ __launch_bounds__(256) void pre_kernel(
    float* __restrict__ xncur, const float* __restrict__ feature, int t,
    const float* __restrict__ xp,      // [2][BN] fc partials from node_kernel
    const float* __restrict__ fb,
    const float* __restrict__ ew1,
    const float* __restrict__ wmean, const float* __restrict__ wstd,
    __half* __restrict__ preS, __half* __restrict__ preT,
    float2* __restrict__ wind2, float* __restrict__ out)
{
    __shared__ alignas(16) float w1s[18 * EHID];
    for (int i = threadIdx.x; i < 18 * EHID; i += 256) w1s[i] = ew1[i];
    __syncthreads();
    int idx = blockIdx.x * 256 + threadIdx.x;
    if (idx >= BN * 8) return;
    int i = idx >> 3;
    int c = idx & 7;
    int b = i / NN, n = i - b * NN;
    float x0;
    if (t == 0) {
        x0 = xncur[i];
    } else {
        x0 = xp[i] + xp[BN + i] + fb[0];
        if (c == 0) {
            xncur[i] = x0;
            out[(size_t)i * PREDC + (t - 1)] = x0;
        }
    }
    float x[9];
    x[0] = x0;
    {
        const float4* fp = reinterpret_cast<const float4*>(
            feature + (((size_t)b * TSTEP + HISTC + t) * NN + n) * FEX);
        float4 u = fp[0], v = fp[1];
        x[1] = u.x; x[2] = u.y; x[3] = u.z; x[4] = u.w;
        x[5] = v.x; x[6] = v.y; x[7] = v.z; x[8] = v.w;
    }
    float4 aS = {0.f, 0.f, 0.f, 0.f}, aT = {0.f, 0.f, 0.f, 0.f};
    #pragma unroll
    for (int k = 0; k < 9; k++) {
        float4 wS = reinterpret_cast<const float4*>(&w1s[k * EHID])[c];
        float4 wT = reinterpret_cast<const float4*>(&w1s[(9 + k) * EHID])[c];
        aS.x += x[k] * wS.x; aS.y += x[k] * wS.y; aS.z += x[k] * wS.z; aS.w += x[k] * wS.w;
        aT.x += x[k] * wT.x; aT.y += x[k] * wT.y; aT.z += x[k] * wT.z; aT.w += x[k] * wT.w;
    }
    union { uint2 u; __half h[4]; } sv, tv;
    sv.h[0] = __float2half(aS.x); sv.h[1] = __float2half(aS.y);
    sv.h[2] = __float2half(aS.z); sv.h[3] = __float2half(aS.w);
    tv.h[0] = __float2half(aT.x); tv.h[1] = __float2half(aT.y);
    tv.h[2] = __float2half(aT.z); tv.h[3] = __float2half(aT.w);
    reinterpret_cast<uint2*>(preS + (size_t)i * EHID)[c] = sv.u;
    reinterpret_cast<uint2*>(preT + (size_t)i * EHID)[c] = tv.u;
    if (c == 1) {
        float sd0 = fmaxf(wstd[0], 1e-6f), sd1 = fmaxf(wstd[1], 1e-6f);
        float speed = fmaxf(x[7] * sd0 + wmean[0], 0.f);
        float wdir  = (x[8] * sd1 + wmean[1]) * 0.017453292519943295f;
        float2 wv; wv.x = 3.0f * speed; wv.y = wdir;
        wind2[i] = wv;
    }
}

// ---------------- final xn/out write for t = PREDC-1 --------------------------
__global__ __launch_bounds__(256) void finalout_kernel(
    const float* __restrict__ xp, const float* __restrict__ fb,
    float* __restrict__ out)
{
    int i = blockIdx.x * 256 + threadIdx.x;
    if (i >= BN) return;
    out[(size_t)i * PREDC + (PREDC - 1)] = xp[i] + xp[BN + i] + fb[0];
}

// ---------------- edge MLP (layers 2,3 + folded n_w) --------------------------
// grid (625, BB); blockIdx.y = batch (x-major dispatch gives temporal batch
// locality in L2). One batch per thread: low VGPR -> high occupancy.
__global__ __launch_bounds__(256) void edge_kernel(
    const int* __restrict__ eidx, const float4* __restrict__ epre4,
    const __half* __restrict__ preS, const __half* __restrict__ preT,
    const float2* __restrict__ wind2,
    const int* __restrict__ pos_t, const int* __restrict__ pos_s,
    const float* __restrict__ ew1, const float* __restrict__ eb1,
    const float* __restrict__ ew2, const float* __restrict__ eb2,
    const float* __restrict__ nw,
    __half* __restrict__ h3t, __half* __restrict__ h3s)
{
    __shared__ alignas(16) float w2t[EOUTC * EHID];    // [o][k]
    __shared__ alignas(16) float nws16[EOUTC * 16];    // [o][j] padded
    __shared__ alignas(16) float w18[EHID], w19[EHID], w20[EHID], b1s[EHID];
    __shared__ float b2s[EOUTC];
    for (int i = threadIdx.x; i < EOUTC * EHID; i += 256) {
        int o = i / EHID, k = i - o * EHID;
        w2t[i] = ew2[k * EOUTC + o];
    }
    for (int i = threadIdx.x; i < EOUTC * 16; i += 256) {
        int o = i >> 4, j = i & 15;
        nws16[i] = (j < GOUTC) ? nw[o * GOUTC + j] : 0.f;
    }
    if (threadIdx.x < EHID) {
        w18[threadIdx.x] = ew1[18 * EHID + threadIdx.x];
        w19[threadIdx.x] = ew1[19 * EHID + threadIdx.x];
        w20[threadIdx.x] = ew1[20 * EHID + threadIdx.x];
        b1s[threadIdx.x] = eb1[threadIdx.x];
    }
    if (threadIdx.x < EOUTC) b2s[threadIdx.x] = eb2[threadIdx.x];
    __syncthreads();

    int e = blockIdx.x * 256 + threadIdx.x;
    if (e >= EE) return;
    int b = blockIdx.y;
    int s = eidx[e];
    int g = eidx[EE + e];
    int pt = pos_t[e];
    int ps = pos_s[e];
    float4 ep = epre4[e];          // {ean0, ean1, 1/dist, direc}

    size_t iS = (size_t)b * NN + s, iT = (size_t)b * NN + g;
    float2 wv2 = wind2[iS];
    float ew = fmaxf(wv2.x * __cosf(fabsf(ep.w - wv2.y)) * ep.z, 0.f);

    union alignas(16) { uint4 u[4]; __half h[EHID]; } RS, RT;
    {
        const uint4* p;
        p = reinterpret_cast<const uint4*>(preS + iS * EHID);
        RS.u[0] = p[0]; RS.u[1] = p[1]; RS.u[2] = p[2]; RS.u[3] = p[3];
        p = reinterpret_cast<const uint4*>(preT + iT * EHID);
        RT.u[0] = p[0]; RT.u[1] = p[1]; RT.u[2] = p[2]; RT.u[3] = p[3];
    }

    float ean0 = ep.x, ean1 = ep.y;
    float h1[EHID];
    #pragma unroll
    for (int q = 0; q < 8; q++) {
        float4 w18q = reinterpret_cast<const float4*>(w18)[q];
        float4 w19q = reinterpret_cast<const float4*>(w19)[q];
        float4 b1q  = reinterpret_cast<const float4*>(b1s)[q];
        float4 w20q = reinterpret_cast<const float4*>(w20)[q];
        float u0 = ean0 * w18q.x + ean1 * w19q.x + b1q.x
                 + __half2float(RS.h[4*q+0]) + __half2float(RT.h[4*q+0]) + w20q.x * ew;
        float u1 = ean0 * w18q.y + ean1 * w19q.y + b1q.y
                 + __half2float(RS.h[4*q+1]) + __half2float(RT.h[4*q+1]) + w20q.y * ew;
        float u2 = ean0 * w18q.z + ean1 * w19q.z + b1q.z
                 + __half2float(RS.h[4*q+2]) + __half2float(RT.h[4*q+2]) + w20q.z * ew;
        float u3 = ean0 * w18q.w + ean1 * w19q.w + b1q.w
                 + __half2float(RS.h[4*q+3]) + __half2float(RT.h[4*q+3]) + w20q.w * ew;
        h1[4*q+0] = sigm(u0);
        h1[4*q+1] = sigm(u1);
        h1[4*q+2] = sigm(u2);
        h1[4*q+3] = sigm(u3);
    }

    float h3[GOUTC];
    #pragma unroll
    for (int j = 0; j < GOUTC; j++) h3[j] = 0.f;

    for (int o = 0; o < EOUTC; o++) {
        float acc = b2s[o];
        const float4* wr = reinterpret_cast<const float4*>(&w2t[o * EHID]);
        #pragma unroll
        for (int q = 0; q < 8; q++) {
            float4 wq = wr[q];
            acc += wq.x * h1[4*q+0] + wq.y * h1[4*q+1]
                 + wq.z * h1[4*q+2] + wq.w * h1[4*q+3];
        }
        float h2 = sigm(acc);
        const float4* nr = reinterpret_cast<const float4*>(&nws16[o * 16]);
        float4 n0 = nr[0], n1 = nr[1], n2 = nr[2], n3 = nr[3];
        h3[0]  += n0.x * h2;  h3[1]  += n0.y * h2;
        h3[2]  += n0.z * h2;  h3[3]  += n0.w * h2;
        h3[4]  += n1.x * h2;  h3[5]  += n1.y * h2;
        h3[6]  += n1.z * h2;  h3[7]  += n1.w * h2;
        h3[8]  += n2.x * h2;  h3[9]  += n2.y * h2;
        h3[10] += n2.z * h2;  h3[11] += n2.w * h2;
        h3[12] += n3.x * h2;
    }

    alignas(16) __half r[16];
    #pragma unroll
    for (int j = 0; j < GOUTC; j++) r[j] = __float2half(h3[j]);
    #pragma unroll
    for (int j = GOUTC; j < 16; j++) r[j] = __float2half(0.f);
    uint4 r0 = reinterpret_cast<const uint4*>(r)[0];
    uint4 r1 = reinterpret_cast<const uint4*>(r)[1];
    {
        __half* oT = h3t + ((size_t)b * EE + pt) * 16;
        reinterpret_cast<uint4*>(oT)[0] = r0;
        reinterpret_cast<uint4*>(oT)[1] = r1;
        __half* oS = h3s + ((size_t)b * EE + ps) * 16;
        reinterpret_cast<uint4*>(oS)[0] = r0;
        reinterpret_cast<uint4*>(oS)[1] = r1;
    }
}

// ---------------- gather: agg13[b][n][ch] = sum_in h3t - sum_out h3s ----------
__global__ __launch_bounds__(256) void gather_kernel(
    const __half* __restrict__ h3t, const __half* __restrict__ h3s,
    const int* __restrict__ off_t, const int* __restrict__ off_s,
    float* __restrict__ agg)
{
    int n = (blockIdx.x * 256 + threadIdx.x) >> 6;
    if (n >= NN) return;
    n = __builtin_amdgcn_readfirstlane(n);
    int lane = threadIdx.x & 63;
    int b = lane >> 4, ch = lane & 15;
    const __half* ht = h3t + (size_t)b * EE * 16 + ch;
    const __half* hs = h3s + (size_t)b * EE * 16 + ch;
    float acc = 0.f;
    int i0 = off_t[n], i1 = off_t[n + 1];
    for (int i = i0; i < i1; i++) {
        acc += __half2float(ht[(size_t)i * 16]);
    }
    i0 = off_s[n]; i1 = off_s[n + 1];
    for (int i = i0; i < i1; i++) {
        acc -= __half2float(hs[(size_t)i * 16]);
    }
    agg[((size_t)b * NN + n) * 16 + ch] = acc;
}

// ---------------- node: gnn-out + GRU + fc partial ----------------------------
// grid (BN/64, 2); block = 64 nodes x 4 waves; wave w of block (.,jb) handles
// hidden dims [jb*32 + w*8, +8). Reads h from hnold, writes hnnew (ping-pong,
// safe across the 2 j-blocks). FC partial -> xp[jb*BN + node].
__global__ __launch_bounds__(256) void node_kernel(
    const float* __restrict__ xncur, const float* __restrict__ feature, int t,
    const float* __restrict__ agg, const float* __restrict__ nb,
    const float* __restrict__ wi, const float* __restrict__ wh,
    const float* __restrict__ bi, const float* __restrict__ bh,
    const float* __restrict__ fw,
    const float* __restrict__ hnold, float* __restrict__ hnnew,
    float* __restrict__ xp)
{
    __shared__ float xpart[4][64];
    int lane = threadIdx.x & 63;
    int wav  = threadIdx.x >> 6;
    int jb   = blockIdx.y;
    int node = blockIdx.x * 64 + lane;
    int b = node / NN;
    int n = node - b * NN;

    float xc[GINC];
    {
        const float4* ar = reinterpret_cast<const float4*>(agg + (size_t)node * 16);
        float4 a0 = ar[0], a1 = ar[1], a2 = ar[2];
        float a3 = agg[(size_t)node * 16 + 12];
        xc[0] = sigm(a0.x + nb[0]);  xc[1] = sigm(a0.y + nb[1]);
        xc[2] = sigm(a0.z + nb[2]);  xc[3] = sigm(a0.w + nb[3]);
        xc[4] = sigm(a1.x + nb[4]);  xc[5] = sigm(a1.y + nb[5]);
        xc[6] = sigm(a1.z + nb[6]);  xc[7] = sigm(a1.w + nb[7]);
        xc[8] = sigm(a2.x + nb[8]);  xc[9] = sigm(a2.y + nb[9]);
        xc[10] = sigm(a2.z + nb[10]); xc[11] = sigm(a2.w + nb[11]);
        xc[12] = sigm(a3 + nb[12]);
    }
    xc[13] = xncur[node];
    {
        const float4* fp = reinterpret_cast<const float4*>(
            feature + (((size_t)b * TSTEP + HISTC + t) * NN + n) * FEX);
        float4 u = fp[0], v = fp[1];
        xc[14] = u.x; xc[15] = u.y; xc[16] = u.z; xc[17] = u.w;
        xc[18] = v.x; xc[19] = v.y; xc[20] = v.z; xc[21] = v.w;
    }

    float h[HIDC];
    #pragma unroll
    for (int k = 0; k < HIDC; k++) h[k] = hnold[(size_t)k * BN + node];

    float xsum = 0.f;
    for (int jj = 0; jj < 8; jj++) {
        int j = __builtin_amdgcn_readfirstlane(jb * 32 + wav * 8 + jj);
        float ir = bi[j], iz = bi[64 + j], in_ = bi[128 + j];
        const float* wr0 = wi + (size_t)j * GINC;
        const float* wr1 = wi + (size_t)(64 + j) * GINC;
        const float* wr2 = wi + (size_t)(128 + j) * GINC;
        #pragma unroll
        for (int k = 0; k < GINC; k++) {
            ir  += wr0[k] * xc[k];
            iz  += wr1[k] * xc[k];
            in_ += wr2[k] * xc[k];
        }
        float hr = bh[j], hz = bh[64 + j], hn_ = bh[128 + j];
        const float* vr0 = wh + (size_t)j * HIDC;
        const float* vr1 = wh + (size_t)(64 + j) * HIDC;
        const float* vr2 = wh + (size_t)(128 + j) * HIDC;
        #pragma unroll
        for (int k = 0; k < HIDC; k++) {
            hr  += vr0[k] * h[k];
            hz  += vr1[k] * h[k];
            hn_ += vr2[k] * h[k];
        }
        float r  = sigm(ir + hr);
        float z  = sigm(iz + hz);
        float nn = tanh_fast(in_ + r * hn_);
        float hold = hnold[(size_t)j * BN + node];   // L1 hit; avoids dyn VGPR index
        float hnew = (1.f - z) * nn + z * hold;
        hnnew[(size_t)j * BN + node] = hnew;
        xsum += hnew * fw[j];
    }
    xpart[wav][lane] = xsum;
    __syncthreads();
    if (wav == 0) {
        float tot = xpart[0][lane] + xpart[1][lane] + xpart[2][lane] + xpart[3][lane];
        xp[(size_t)jb * BN + node] = tot;
    }
}

extern "C" void kernel_launch(void* const* d_in, const int* in_sizes, int n_in,
                              void* d_out, int out_size, void* d_ws, size_t ws_size,
                              hipStream_t stream)
{
    const float* pm    = (const float*)d_in[0];
    const float* feat  = (const float*)d_in[1];
    const float* ea    = (const float*)d_in[2];
    const float* wmean = (const float*)d_in[3];
    const float* wstd  = (const float*)d_in[4];
    const float* ew1   = (const float*)d_in[5];
    const float* eb1   = (const float*)d_in[6];
    const float* ew2   = (const float*)d_in[7];
    const float* eb2   = (const float*)d_in[8];
    const float* nw    = (const float*)d_in[9];
    const float* nb    = (const float*)d_in[10];
    const float* wi    = (const float*)d_in[11];
    const float* wh    = (const float*)d_in[12];
    const float* bi    = (const float*)d_in[13];
    const float* bh    = (const float*)d_in[14];
    const float* fw    = (const float*)d_in[15];
    const float* fb    = (const float*)d_in[16];
    const int*   eidx  = (const int*)d_in[17];
    float* out = (float*)d_out;

    char* w = (char*)d_ws;
    double* partd = (double*)w;                    w += 256 * 4 * sizeof(double);
    float*  stats = (float*)w;                     w += 16 * sizeof(float);
    float4* epre4 = (float4*)w;                    w += (size_t)EE * sizeof(float4);
    float*  xncur = (float*)w;                     w += (size_t)BN * sizeof(float);
    float*  xp    = (float*)w;                     w += (size_t)2 * BN * sizeof(float);
    float*  hnA   = (float*)w;                     w += (size_t)HIDC * BN * sizeof(float);
    float*  hnB   = (float*)w;                     w += (size_t)HIDC * BN * sizeof(float);
    float*  agg13 = (float*)w;                     w += (size_t)BN * 16 * sizeof(float);
    __half* preS  = (__half*)w;                    w += (size_t)BN * EHID * sizeof(__half);
    __half* preT  = (__half*)w;                    w += (size_t)BN * EHID * sizeof(__half);
    float2* wind2 = (float2*)w;                    w += (size_t)BN * sizeof(float2);
    __half* h3t   = (__half*)w;                    w += (size_t)BB * EE * 16 * sizeof(__half);
    __half* h3s   = (__half*)w;                    w += (size_t)BB * EE * 16 * sizeof(__half);
    int*    deg_t = (int*)w;                       w += NN * sizeof(int);
    int*    deg_s = (int*)w;                       w += NN * sizeof(int);
    int*    off_t = (int*)w;                       w += (NN + 1) * sizeof(int);
    int*    off_s = (int*)w;                       w += (NN + 1) * sizeof(int);
    int*    cnt_t = (int*)w;                       w += NN * sizeof(int);
    int*    cnt_s = (int*)w;                       w += NN * sizeof(int);
    int*    pos_t = (int*)w;                       w += (size_t)EE * sizeof(int);
    int*    pos_s = (int*)w;                       w += (size_t)EE * sizeof(int);

    stats1_kernel<<<256, 256, 0, stream>>>(ea, partd);
    stats2_kernel<<<1, 256, 0, stream>>>(partd, stats);
    edgepre_kernel<<<(EE + 255) / 256, 256, 0, stream>>>(ea, stats, epre4);
    initxn_kernel<<<(BN + 255) / 256, 256, 0, stream>>>(pm, xncur);
    hipMemsetAsync(hnA, 0, (size_t)HIDC * BN * sizeof(float), stream);
    hipMemsetAsync(deg_t, 0, 2 * NN * sizeof(int), stream);
    hist_kernel<<<(EE + 255) / 256, 256, 0, stream>>>(eidx, deg_t, deg_s);
    scan_kernel<<<1, 1024, 0, stream>>>(deg_t, deg_s, off_t, off_s, cnt_t, cnt_s);
    fill_kernel<<<(EE + 255) / 256, 256, 0, stream>>>(eidx, cnt_t, cnt_s, pos_t, pos_s);

    for (int t = 0; t < PREDC; t++) {
        const float* hnold = (t & 1) ? hnB : hnA;
        float*       hnnew = (t & 1) ? hnA : hnB;
        pre_kernel<<<(BN * 8 + 255) / 256, 256, 0, stream>>>(
            xncur, feat, t, xp, fb, ew1, wmean, wstd, preS, preT, wind2, out);
        edge_kernel<<<dim3((EE + 255) / 256, BB), 256, 0, stream>>>(
            eidx, epre4, preS, preT, wind2, pos_t, pos_s,
            ew1, eb1, ew2, eb2, nw, h3t, h3s);
        gather_kernel<<<(NN * 64 + 255) / 256, 256, 0, stream>>>(
            h3t, h3s, off_t, off_s, agg13);
        node_kernel<<<dim3(BN / 64, 2), 256, 0, stream>>>(
            xncur, feat, t, agg13, nb, wi, wh, bi, bh, fw, hnold, hnnew, xp);
    }
    finalout_kernel<<<(BN + 255) / 256, 256, 0, stream>>>(xp, fb, out);
}

// Round 7
// 1695.972 us; speedup vs baseline: 1.3571x; 1.0217x over previous
//
#include <hip/hip_runtime.h>
#include <hip/hip_fp16.h>
#include <cstddef>

#define BB    4
#define NN    10000
#define EE    160000
#define BN    40000      // BB*NN
#define HISTC 8
#define PREDC 12
#define TSTEP 20         // HIST+PRED
#define FEX   8
#define HIDC  64
#define EHID  32
#define EOUTC 30
#define GOUTC 13
#define GINC  22         // GOUTC + 9

typedef float v2f __attribute__((ext_vector_type(2)));

__device__ __forceinline__ float fast_rcp(float x) { return __builtin_amdgcn_rcpf(x); }
__device__ __forceinline__ float sigm(float x) {
    return fast_rcp(1.0f + __expf(-x));
}
__device__ __forceinline__ v2f sigm2(v2f x) {
    v2f r; r.x = sigm(x.x); r.y = sigm(x.y); return r;
}
__device__ __forceinline__ float tanh_fast(float x) {
    x = fminf(fmaxf(x, -15.0f), 15.0f);
    float e = __expf(2.0f * x);
    return (e - 1.0f) * fast_rcp(e + 1.0f);
}

// ---------------- edge_attr stats: stage 1 (per-block partials) ---------------
__global__ __launch_bounds__(256) void stats1_kernel(const float* __restrict__ ea,
                                                     double* __restrict__ part) {
    __shared__ double sm[256][4];
    int tid = threadIdx.x;
    double s0 = 0, s1 = 0, q0 = 0, q1 = 0;
    for (int e = blockIdx.x * 256 + tid; e < EE; e += 256 * 256) {
        float2 v = reinterpret_cast<const float2*>(ea)[e];
        double v0 = (double)v.x, v1 = (double)v.y;
        s0 += v0; q0 += v0 * v0;
        s1 += v1; q1 += v1 * v1;
    }
    sm[tid][0] = s0; sm[tid][1] = s1; sm[tid][2] = q0; sm[tid][3] = q1;
    __syncthreads();
    for (int off = 128; off > 0; off >>= 1) {
        if (tid < off)
            for (int k = 0; k < 4; k++) sm[tid][k] += sm[tid + off][k];
        __syncthreads();
    }
    if (tid == 0) {
        part[blockIdx.x * 4 + 0] = sm[0][0];
        part[blockIdx.x * 4 + 1] = sm[0][1];
        part[blockIdx.x * 4 + 2] = sm[0][2];
        part[blockIdx.x * 4 + 3] = sm[0][3];
    }
}

__global__ __launch_bounds__(256) void stats2_kernel(const double* __restrict__ part,
                                                     float* __restrict__ stats) {
    __shared__ double sm[256][4];
    int tid = threadIdx.x;
    sm[tid][0] = part[tid * 4 + 0];
    sm[tid][1] = part[tid * 4 + 1];
    sm[tid][2] = part[tid * 4 + 2];
    sm[tid][3] = part[tid * 4 + 3];
    __syncthreads();
    for (int off = 128; off > 0; off >>= 1) {
        if (tid < off)
            for (int k = 0; k < 4; k++) sm[tid][k] += sm[tid + off][k];
        __syncthreads();
    }
    if (tid == 0) {
        double m0 = sm[0][0] / EE, m1 = sm[0][1] / EE;
        double v0 = (sm[0][2] - sm[0][0] * sm[0][0] / EE) / (double)(EE - 1);
        double v1 = (sm[0][3] - sm[0][1] * sm[0][1] / EE) / (double)(EE - 1);
        float sd0 = fmaxf((float)sqrt(v0 > 0 ? v0 : 0.0), 1e-6f);
        float sd1 = fmaxf((float)sqrt(v1 > 0 ? v1 : 0.0), 1e-6f);
        stats[0] = (float)m0; stats[1] = (float)m1;
        stats[2] = 1.0f / sd0; stats[3] = 1.0f / sd1;
    }
}

// ---------------- per-edge precompute: epre4 = {ean0, ean1, 1/dist, direc} ----
__global__ __launch_bounds__(256) void edgepre_kernel(
    const float* __restrict__ ea, const float* __restrict__ stats,
    float4* __restrict__ epre4)
{
    int e = blockIdx.x * 256 + threadIdx.x;
    if (e >= EE) return;
    float2 v = reinterpret_cast<const float2*>(ea)[e];
    float4 r;
    r.x = (v.x - stats[0]) * stats[2];
    r.y = (v.y - stats[1]) * stats[3];
    r.z = 1.0f / fmaxf(v.x, 1e-3f);
    r.w = v.y;
    epre4[e] = r;
}

// ---------------- xn init from pm25_hist[:, -1] -------------------------------
__global__ void initxn_kernel(const float* __restrict__ pm, float* __restrict__ xn) {
    int i = blockIdx.x * 256 + threadIdx.x;
    if (i >= BN) return;
    int b = i / NN, n = i - b * NN;
    xn[i] = pm[(b * HISTC + (HISTC - 1)) * NN + n];
}

// ---------------- CSR build (once per call) -----------------------------------
__global__ void hist_kernel(const int* __restrict__ eidx,
                            int* __restrict__ deg_t, int* __restrict__ deg_s) {
    int e = blockIdx.x * 256 + threadIdx.x;
    if (e >= EE) return;
    atomicAdd(&deg_s[eidx[e]], 1);
    atomicAdd(&deg_t[eidx[EE + e]], 1);
}

__global__ __launch_bounds__(1024) void scan_kernel(
    const int* __restrict__ deg_t, const int* __restrict__ deg_s,
    int* __restrict__ off_t, int* __restrict__ off_s,
    int* __restrict__ cnt_t, int* __restrict__ cnt_s)
{
    __shared__ int pt[1024], ps[1024];
    int tid = threadIdx.x;
    int base = tid * 10;
    int st = 0, ss = 0;
    for (int k = 0; k < 10; k++) {
        int i = base + k;
        if (i < NN) { st += deg_t[i]; ss += deg_s[i]; }
    }
    pt[tid] = st; ps[tid] = ss;
    __syncthreads();
    for (int off = 1; off < 1024; off <<= 1) {
        int vt = (tid >= off) ? pt[tid - off] : 0;
        int vs = (tid >= off) ? ps[tid - off] : 0;
        __syncthreads();
        pt[tid] += vt; ps[tid] += vs;
        __syncthreads();
    }
    int ext = (tid == 0) ? 0 : pt[tid - 1];
    int exs = (tid == 0) ? 0 : ps[tid - 1];
    for (int k = 0; k < 10; k++) {
        int i = base + k;
        if (i < NN) {
            off_t[i] = ext; cnt_t[i] = ext;
            off_s[i] = exs; cnt_s[i] = exs;
            ext += deg_t[i]; exs += deg_s[i];
        }
    }
    if (tid == 0) { off_t[NN] = EE; off_s[NN] = EE; }
}

__global__ void fill_kernel(const int* __restrict__ eidx,
                            int* __restrict__ cnt_t, int* __restrict__ cnt_s,
                            int* __restrict__ pos_t, int* __restrict__ pos_s)
{
    int e = blockIdx.x * 256 + threadIdx.x;
    if (e >= EE) return;
    int s = eidx[e];
    int g = eidx[EE + e];
    pos_t[e] = atomicAdd(&cnt_t[g], 1);
    pos_s[e] = atomicAdd(&cnt_s[s], 1);
}

// ---------------- per-step node precompute (fp16 tables) + xn/out finalize ----
__global__ __launch_bounds__(256) void pre_kernel(
    float* __restrict__ xncur, const float* __restrict__ feature, int t,
    const float* __restrict__ xp,      // [2][BN] fc partials from node_kernel
    const float* __restrict__ fb,
    const float* __restrict__ ew1,
    const float* __restrict__ wmean, const float* __restrict__ wstd,
    __half* __restrict__ preS, __half* __restrict__ preT,
    float2* __restrict__ wind2, float* __restrict__ out)
{
    __shared__ alignas(16) float w1s[18 * EHID];
    for (int i = threadIdx.x; i < 18 * EHID; i += 256) w1s[i] = ew1[i];
    __syncthreads();
    int idx = blockIdx.x * 256 + threadIdx.x;
    if (idx >= BN * 8) return;
    int i = idx >> 3;
    int c = idx & 7;
    int b = i / NN, n = i - b * NN;
    float x0;
    if (t == 0) {
        x0 = xncur[i];
    } else {
        x0 = xp[i] + xp[BN + i] + fb[0];
        if (c == 0) {
            xncur[i] = x0;
            out[(size_t)i * PREDC + (t - 1)] = x0;
        }
    }
    float x[9];
    x[0] = x0;
    {
        const float4* fp = reinterpret_cast<const float4*>(
            feature + (((size_t)b * TSTEP + HISTC + t) * NN + n) * FEX);
        float4 u = fp[0], v = fp[1];
        x[1] = u.x; x[2] = u.y; x[3] = u.z; x[4] = u.w;
        x[5] = v.x; x[6] = v.y; x[7] = v.z; x[8] = v.w;
    }
    float4 aS = {0.f, 0.f, 0.f, 0.f}, aT = {0.f, 0.f, 0.f, 0.f};
    #pragma unroll
    for (int k = 0; k < 9; k++) {
        float4 wS = reinterpret_cast<const float4*>(&w1s[k * EHID])[c];
        float4 wT = reinterpret_cast<const float4*>(&w1s[(9 + k) * EHID])[c];
        aS.x += x[k] * wS.x; aS.y += x[k] * wS.y; aS.z += x[k] * wS.z; aS.w += x[k] * wS.w;
        aT.x += x[k] * wT.x; aT.y += x[k] * wT.y; aT.z += x[k] * wT.z; aT.w += x[k] * wT.w;
    }
    union { uint2 u; __half h[4]; } sv, tv;
    sv.h[0] = __float2half(aS.x); sv.h[1] = __float2half(aS.y);
    sv.h[2] = __float2half(aS.z); sv.h[3] = __float2half(aS.w);
    tv.h[0] = __float2half(aT.x); tv.h[1] = __float2half(aT.y);
    tv.h[2] = __float2half(aT.z); tv.h[3] = __float2half(aT.w);
    reinterpret_cast<uint2*>(preS + (size_t)i * EHID)[c] = sv.u;
    reinterpret_cast<uint2*>(preT + (size_t)i * EHID)[c] = tv.u;
    if (c == 1) {
        float sd0 = fmaxf(wstd[0], 1e-6f), sd1 = fmaxf(wstd[1], 1e-6f);
        float speed = fmaxf(x[7] * sd0 + wmean[0], 0.f);
        float wdir  = (x[8] * sd1 + wmean[1]) * 0.017453292519943295f;
        float2 wv; wv.x = 3.0f * speed; wv.y = wdir;
        wind2[i] = wv;
    }
}

// ---------------- final xn/out write for t = PREDC-1 --------------------------
__global__ __launch_bounds__(256) void finalout_kernel(
    const float* __restrict__ xp, const float* __restrict__ fb,
    float* __restrict__ out)
{
    int i = blockIdx.x * 256 + threadIdx.x;
    if (i >= BN) return;
    out[(size_t)i * PREDC + (PREDC - 1)] = xp[i] + xp[BN + i] + fb[0];
}

// ---------------- edge MLP (layers 2,3 + folded n_w), packed fp32 -------------
// grid (625, BB); blockIdx.y = batch. All FMA chains paired -> v_pk_fma_f32.
__global__ __launch_bounds__(256) void edge_kernel(
    const int* __restrict__ eidx, const float4* __restrict__ epre4,
    const __half* __restrict__ preS, const __half* __restrict__ preT,
    const float2* __restrict__ wind2,
    const int* __restrict__ pos_t, const int* __restrict__ pos_s,
    const float* __restrict__ ew1, const float* __restrict__ eb1,
    const float* __restrict__ ew2, const float* __restrict__ eb2,
    const float* __restrict__ nw,
    __half* __restrict__ h3t, __half* __restrict__ h3s)
{
    __shared__ alignas(16) float w2t[EOUTC * EHID];    // [o][k]
    __shared__ alignas(16) float nws16[EOUTC * 16];    // [o][j] padded
    __shared__ alignas(16) float w18[EHID], w19[EHID], w20[EHID], b1s[EHID];
    __shared__ float b2s[EOUTC];
    for (int i = threadIdx.x; i < EOUTC * EHID; i += 256) {
        int o = i / EHID, k = i - o * EHID;
        w2t[i] = ew2[k * EOUTC + o];
    }
    for (int i = threadIdx.x; i < EOUTC * 16; i += 256) {
        int o = i >> 4, j = i & 15;
        nws16[i] = (j < GOUTC) ? nw[o * GOUTC + j] : 0.f;
    }
    if (threadIdx.x < EHID) {
        w18[threadIdx.x] = ew1[18 * EHID + threadIdx.x];
        w19[threadIdx.x] = ew1[19 * EHID + threadIdx.x];
        w20[threadIdx.x] = ew1[20 * EHID + threadIdx.x];
        b1s[threadIdx.x] = eb1[threadIdx.x];
    }
    if (threadIdx.x < EOUTC) b2s[threadIdx.x] = eb2[threadIdx.x];
    __syncthreads();

    int e = blockIdx.x * 256 + threadIdx.x;
    if (e >= EE) return;
    int b = blockIdx.y;
    int s = eidx[e];
    int g = eidx[EE + e];
    int pt = pos_t[e];
    int ps = pos_s[e];
    float4 ep = epre4[e];          // {ean0, ean1, 1/dist, direc}

    size_t iS = (size_t)b * NN + s, iT = (size_t)b * NN + g;
    float2 wv2 = wind2[iS];
    float ew = fmaxf(wv2.x * __cosf(fabsf(ep.w - wv2.y)) * ep.z, 0.f);

    union alignas(16) { uint4 u[4]; __half2 h2[16]; } RS, RT;
    {
        const uint4* p;
        p = reinterpret_cast<const uint4*>(preS + iS * EHID);
        RS.u[0] = p[0]; RS.u[1] = p[1]; RS.u[2] = p[2]; RS.u[3] = p[3];
        p = reinterpret_cast<const uint4*>(preT + iT * EHID);
        RT.u[0] = p[0]; RT.u[1] = p[1]; RT.u[2] = p[2]; RT.u[3] = p[3];
    }

    float ean0 = ep.x, ean1 = ep.y;
    // layer 1: 16 channel-pairs, all packed fp32
    v2f h1p[16];
    #pragma unroll
    for (int q = 0; q < 16; q++) {
        v2f w18q = reinterpret_cast<const v2f*>(w18)[q];
        v2f w19q = reinterpret_cast<const v2f*>(w19)[q];
        v2f w20q = reinterpret_cast<const v2f*>(w20)[q];
        v2f b1q  = reinterpret_cast<const v2f*>(b1s)[q];
        float2 rs = __half22float2(RS.h2[q]);
        float2 rt = __half22float2(RT.h2[q]);
        v2f rsv; rsv.x = rs.x; rsv.y = rs.y;
        v2f rtv; rtv.x = rt.x; rtv.y = rt.y;
        v2f u = w18q * ean0 + w19q * ean1 + b1q + rsv + rtv + w20q * ew;
        h1p[q] = sigm2(u);
    }

    // layers 2+3: pk_fma over k-pairs, then pk_fma over j-pairs
    v2f h3p[7];
    #pragma unroll
    for (int j = 0; j < 7; j++) { h3p[j].x = 0.f; h3p[j].y = 0.f; }

    for (int o = 0; o < EOUTC; o++) {
        v2f accp; accp.x = 0.f; accp.y = 0.f;
        const v2f* wr = reinterpret_cast<const v2f*>(&w2t[o * EHID]);
        #pragma unroll
        for (int q = 0; q < 16; q++) accp += wr[q] * h1p[q];
        float h2 = sigm(accp.x + accp.y + b2s[o]);
        const v2f* nr = reinterpret_cast<const v2f*>(&nws16[o * 16]);
        #pragma unroll
        for (int j = 0; j < 7; j++) h3p[j] += nr[j] * h2;
    }

    union alignas(16) { uint4 u[2]; __half2 h2[8]; } r;
    #pragma unroll
    for (int j = 0; j < 7; j++) r.h2[j] = __floats2half2_rn(h3p[j].x, h3p[j].y);
    r.h2[7] = __floats2half2_rn(0.f, 0.f);
    {
        __half* oT = h3t + ((size_t)b * EE + pt) * 16;
        reinterpret_cast<uint4*>(oT)[0] = r.u[0];
        reinterpret_cast<uint4*>(oT)[1] = r.u[1];
        __half* oS = h3s + ((size_t)b * EE + ps) * 16;
        reinterpret_cast<uint4*>(oS)[0] = r.u[0];
        reinterpret_cast<uint4*>(oS)[1] = r.u[1];
    }
}

// ---------------- gather: agg13[b][n][ch] = sum_in h3t - sum_out h3s ----------
__global__ __launch_bounds__(256) void gather_kernel(
    const __half* __restrict__ h3t, const __half* __restrict__ h3s,
    const int* __restrict__ off_t, const int* __restrict__ off_s,
    float* __restrict__ agg)
{
    int n = (blockIdx.x * 256 + threadIdx.x) >> 6;
    if (n >= NN) return;
    n = __builtin_amdgcn_readfirstlane(n);
    int lane = threadIdx.x & 63;
    int b = lane >> 4, ch = lane & 15;
    const __half* ht = h3t + (size_t)b * EE * 16 + ch;
    const __half* hs = h3s + (size_t)b * EE * 16 + ch;
    float acc = 0.f;
    int i0 = off_t[n], i1 = off_t[n + 1];
    for (int i = i0; i < i1; i++) {
        acc += __half2float(ht[(size_t)i * 16]);
    }
    i0 = off_s[n]; i1 = off_s[n + 1];
    for (int i = i0; i < i1; i++) {
        acc -= __half2float(hs[(size_t)i * 16]);
    }
    agg[((size_t)b * NN + n) * 16 + ch] = acc;
}

// ---------------- node: gnn-out + GRU + fc partial ----------------------------
// grid (BN/64, 2); wave w of block (.,jb) handles dims [jb*32+w*8, +8).
__global__ __launch_bounds__(256) void node_kernel(
    const float* __restrict__ xncur, const float* __restrict__ feature, int t,
    const float* __restrict__ agg, const float* __restrict__ nb,
    const float* __restrict__ wi, const float* __restrict__ wh,
    const float* __restrict__ bi, const float* __restrict__ bh,
    const float* __restrict__ fw,
    const float* __restrict__ hnold, float* __restrict__ hnnew,
    float* __restrict__ xp)
{
    __shared__ float xpart[4][64];
    int lane = threadIdx.x & 63;
    int wav  = threadIdx.x >> 6;
    int jb   = blockIdx.y;
    int node = blockIdx.x * 64 + lane;
    int b = node / NN;
    int n = node - b * NN;

    float xc[GINC];
    {
        const float4* ar = reinterpret_cast<const float4*>(agg + (size_t)node * 16);
        float4 a0 = ar[0], a1 = ar[1], a2 = ar[2];
        float a3 = agg[(size_t)node * 16 + 12];
        xc[0] = sigm(a0.x + nb[0]);  xc[1] = sigm(a0.y + nb[1]);
        xc[2] = sigm(a0.z + nb[2]);  xc[3] = sigm(a0.w + nb[3]);
        xc[4] = sigm(a1.x + nb[4]);  xc[5] = sigm(a1.y + nb[5]);
        xc[6] = sigm(a1.z + nb[6]);  xc[7] = sigm(a1.w + nb[7]);
        xc[8] = sigm(a2.x + nb[8]);  xc[9] = sigm(a2.y + nb[9]);
        xc[10] = sigm(a2.z + nb[10]); xc[11] = sigm(a2.w + nb[11]);
        xc[12] = sigm(a3 + nb[12]);
    }
    xc[13] = xncur[node];
    {
        const float4* fp = reinterpret_cast<const float4*>(
            feature + (((size_t)b * TSTEP + HISTC + t) * NN + n) * FEX);
        float4 u = fp[0], v = fp[1];
        xc[14] = u.x; xc[15] = u.y; xc[16] = u.z; xc[17] = u.w;
        xc[18] = v.x; xc[19] = v.y; xc[20] = v.z; xc[21] = v.w;
    }

    float h[HIDC];
    #pragma unroll
    for (int k = 0; k < HIDC; k++) h[k] = hnold[(size_t)k * BN + node];

    float xsum = 0.f;
    for (int jj = 0; jj < 8; jj++) {
        int j = __builtin_amdgcn_readfirstlane(jb * 32 + wav * 8 + jj);
        float ir = bi[j], iz = bi[64 + j], in_ = bi[128 + j];
        const float* wr0 = wi + (size_t)j * GINC;
        const float* wr1 = wi + (size_t)(64 + j) * GINC;
        const float* wr2 = wi + (size_t)(128 + j) * GINC;
        #pragma unroll
        for (int k = 0; k < GINC; k++) {
            ir  += wr0[k] * xc[k];
            iz  += wr1[k] * xc[k];
            in_ += wr2[k] * xc[k];
        }
        float hr = bh[j], hz = bh[64 + j], hn_ = bh[128 + j];
        const float* vr0 = wh + (size_t)j * HIDC;
        const float* vr1 = wh + (size_t)(64 + j) * HIDC;
        const float* vr2 = wh + (size_t)(128 + j) * HIDC;
        #pragma unroll
        for (int k = 0; k < HIDC; k++) {
            hr  += vr0[k] * h[k];
            hz  += vr1[k] * h[k];
            hn_ += vr2[k] * h[k];
        }
        float r  = sigm(ir + hr);
        float z  = sigm(iz + hz);
        float nn = tanh_fast(in_ + r * hn_);
        float hold = hnold[(size_t)j * BN + node];
        float hnew = (1.f - z) * nn + z * hold;
        hnnew[(size_t)j * BN + node] = hnew;
        xsum += hnew * fw[j];
    }
    xpart[wav][lane] = xsum;
    __syncthreads();
    if (wav == 0) {
        float tot = xpart[0][lane] + xpart[1][lane] + xpart[2][lane] + xpart[3][lane];
        xp[(size_t)jb * BN + node] = tot;
    }
}

extern "C" void kernel_launch(void* const* d_in, const int* in_sizes, int n_in,
                              void* d_out, int out_size, void* d_ws, size_t ws_size,
                              hipStream_t stream)
{
    const float* pm    = (const float*)d_in[0];
    const float* feat  = (const float*)d_in[1];
    const float* ea    = (const float*)d_in[2];
    const float* wmean = (const float*)d_in[3];
    const float* wstd  = (const float*)d_in[4];
    const float* ew1   = (const float*)d_in[5];
    const float* eb1   = (const float*)d_in[6];
    const float* ew2   = (const float*)d_in[7];
    const float* eb2   = (const float*)d_in[8];
    const float* nw    = (const float*)d_in[9];
    const float* nb    = (const float*)d_in[10];
    const float* wi    = (const float*)d_in[11];
    const float* wh    = (const float*)d_in[12];
    const float* bi    = (const float*)d_in[13];
    const float* bh    = (const float*)d_in[14];
    const float* fw    = (const float*)d_in[15];
    const float* fb    = (const float*)d_in[16];
    const int*   eidx  = (const int*)d_in[17];
    float* out = (float*)d_out;

    char* w = (char*)d_ws;
    double* partd = (double*)w;                    w += 256 * 4 * sizeof(double);
    float*  stats = (float*)w;                     w += 16 * sizeof(float);
    float4* epre4 = (float4*)w;                    w += (size_t)EE * sizeof(float4);
    float*  xncur = (float*)w;                     w += (size_t)BN * sizeof(float);
    float*  xp    = (float*)w;                     w += (size_t)2 * BN * sizeof(float);
    float*  hnA   = (float*)w;                     w += (size_t)HIDC * BN * sizeof(float);
    float*  hnB   = (float*)w;                     w += (size_t)HIDC * BN * sizeof(float);
    float*  agg13 = (float*)w;                     w += (size_t)BN * 16 * sizeof(float);
    __half* preS  = (__half*)w;                    w += (size_t)BN * EHID * sizeof(__half);
    __half* preT  = (__half*)w;                    w += (size_t)BN * EHID * sizeof(__half);
    float2* wind2 = (float2*)w;                    w += (size_t)BN * sizeof(float2);
    __half* h3t   = (__half*)w;                    w += (size_t)BB * EE * 16 * sizeof(__half);
    __half* h3s   = (__half*)w;                    w += (size_t)BB * EE * 16 * sizeof(__half);
    int*    deg_t = (int*)w;                       w += NN * sizeof(int);
    int*    deg_s = (int*)w;                       w += NN * sizeof(int);
    int*    off_t = (int*)w;                       w += (NN + 1) * sizeof(int);
    int*    off_s = (int*)w;                       w += (NN + 1) * sizeof(int);
    int*    cnt_t = (int*)w;                       w += NN * sizeof(int);
    int*    cnt_s = (int*)w;                       w += NN * sizeof(int);
    int*    pos_t = (int*)w;                       w += (size_t)EE * sizeof(int);
    int*    pos_s = (int*)w;                       w += (size_t)EE * sizeof(int);

    stats1_kernel<<<256, 256, 0, stream>>>(ea, partd);
    stats2_kernel<<<1, 256, 0, stream>>>(partd, stats);
    edgepre_kernel<<<(EE + 255) / 256, 256, 0, stream>>>(ea, stats, epre4);
    initxn_kernel<<<(BN + 255) / 256, 256, 0, stream>>>(pm, xncur);
    hipMemsetAsync(hnA, 0, (size_t)HIDC * BN * sizeof(float), stream);
    hipMemsetAsync(deg_t, 0, 2 * NN * sizeof(int), stream);
    hist_kernel<<<(EE + 255) / 256, 256, 0, stream>>>(eidx, deg_t, deg_s);
    scan_kernel<<<1, 1024, 0, stream>>>(deg_t, deg_s, off_t, off_s, cnt_t, cnt_s);
    fill_kernel<<<(EE + 255) / 256, 256, 0, stream>>>(eidx, cnt_t, cnt_s, pos_t, pos_s);

    for (int t = 0; t < PREDC; t++) {
        const float* hnold = (t & 1) ? hnB : hnA;
        float*       hnnew = (t & 1) ? hnA : hnB;
        pre_kernel<<<(BN * 8 + 255) / 256, 256, 0, stream>>>(
            xncur, feat, t, xp, fb, ew1, wmean, wstd, preS, preT, wind2, out);
        edge_kernel<<<dim3((EE + 255) / 256, BB), 256, 0, stream>>>(
            eidx, epre4, preS, preT, wind2, pos_t, pos_s,
            ew1, eb1, ew2, eb2, nw, h3t, h3s);
        gather_kernel<<<(NN * 64 + 255) / 256, 256, 0, stream>>>(
            h3t, h3s, off_t, off_s, agg13);
        node_kernel<<<dim3(BN / 64, 2), 256, 0, stream>>>(
            xncur, feat, t, agg13, nb, wi, wh, bi, bh, fw, hnold, hnnew, xp);
    }
    finalout_kernel<<<(BN + 255) / 256, 256, 0, stream>>>(xp, fb, out);
}

// Round 8
// 1317.303 us; speedup vs baseline: 1.7472x; 1.2875x over previous
//
#include <hip/hip_runtime.h>
#include <hip/hip_fp16.h>
#include <cstddef>

#define BB    4
#define NN    10000
#define EE    160000
#define BN    40000      // BB*NN
#define HISTC 8
#define PREDC 12
#define TSTEP 20         // HIST+PRED
#define FEX   8
#define HIDC  64
#define EHID  32
#define EOUTC 30
#define GOUTC 13
#define GINC  22         // GOUTC + 9

typedef float v2f __attribute__((ext_vector_type(2)));
typedef _Float16 v2h __attribute__((ext_vector_type(2)));

__device__ __forceinline__ float fast_rcp(float x) { return __builtin_amdgcn_rcpf(x); }
__device__ __forceinline__ float sigm(float x) {
    return fast_rcp(1.0f + __expf(-x));
}
__device__ __forceinline__ v2f sigm2(v2f x) {
    v2f r; r.x = sigm(x.x); r.y = sigm(x.y); return r;
}
__device__ __forceinline__ float tanh_fast(float x) {
    x = fminf(fmaxf(x, -15.0f), 15.0f);
    float e = __expf(2.0f * x);
    return (e - 1.0f) * fast_rcp(e + 1.0f);
}

// packed fp16 dot with fp32 accumulate (v_dot2_f32_f16)
__device__ __forceinline__ float dot2(__half2 a, __half2 b, float c) {
#if __has_builtin(__builtin_amdgcn_fdot2)
    union { __half2 h; v2h v; } ua, ub;
    ua.h = a; ub.h = b;
    return __builtin_amdgcn_fdot2(ua.v, ub.v, c, false);
#else
    float2 fa = __half22float2(a), fb = __half22float2(b);
    return c + fa.x * fb.x + fa.y * fb.y;
#endif
}

// ---------------- edge_attr stats ---------------------------------------------
__global__ __launch_bounds__(256) void stats1_kernel(const float* __restrict__ ea,
                                                     double* __restrict__ part) {
    __shared__ double sm[256][4];
    int tid = threadIdx.x;
    double s0 = 0, s1 = 0, q0 = 0, q1 = 0;
    for (int e = blockIdx.x * 256 + tid; e < EE; e += 256 * 256) {
        float2 v = reinterpret_cast<const float2*>(ea)[e];
        double v0 = (double)v.x, v1 = (double)v.y;
        s0 += v0; q0 += v0 * v0;
        s1 += v1; q1 += v1 * v1;
    }
    sm[tid][0] = s0; sm[tid][1] = s1; sm[tid][2] = q0; sm[tid][3] = q1;
    __syncthreads();
    for (int off = 128; off > 0; off >>= 1) {
        if (tid < off)
            for (int k = 0; k < 4; k++) sm[tid][k] += sm[tid + off][k];
        __syncthreads();
    }
    if (tid == 0) {
        part[blockIdx.x * 4 + 0] = sm[0][0];
        part[blockIdx.x * 4 + 1] = sm[0][1];
        part[blockIdx.x * 4 + 2] = sm[0][2];
        part[blockIdx.x * 4 + 3] = sm[0][3];
    }
}

__global__ __launch_bounds__(256) void stats2_kernel(const double* __restrict__ part,
                                                     float* __restrict__ stats) {
    __shared__ double sm[256][4];
    int tid = threadIdx.x;
    sm[tid][0] = part[tid * 4 + 0];
    sm[tid][1] = part[tid * 4 + 1];
    sm[tid][2] = part[tid * 4 + 2];
    sm[tid][3] = part[tid * 4 + 3];
    __syncthreads();
    for (int off = 128; off > 0; off >>= 1) {
        if (tid < off)
            for (int k = 0; k < 4; k++) sm[tid][k] += sm[tid + off][k];
        __syncthreads();
    }
    if (tid == 0) {
        double m0 = sm[0][0] / EE, m1 = sm[0][1] / EE;
        double v0 = (sm[0][2] - sm[0][0] * sm[0][0] / EE) / (double)(EE - 1);
        double v1 = (sm[0][3] - sm[0][1] * sm[0][1] / EE) / (double)(EE - 1);
        float sd0 = fmaxf((float)sqrt(v0 > 0 ? v0 : 0.0), 1e-6f);
        float sd1 = fmaxf((float)sqrt(v1 > 0 ? v1 : 0.0), 1e-6f);
        stats[0] = (float)m0; stats[1] = (float)m1;
        stats[2] = 1.0f / sd0; stats[3] = 1.0f / sd1;
    }
}

// ---------------- per-edge precompute -----------------------------------------
__global__ __launch_bounds__(256) void edgepre_kernel(
    const float* __restrict__ ea, const float* __restrict__ stats,
    float4* __restrict__ epre4)
{
    int e = blockIdx.x * 256 + threadIdx.x;
    if (e >= EE) return;
    float2 v = reinterpret_cast<const float2*>(ea)[e];
    float4 r;
    r.x = (v.x - stats[0]) * stats[2];
    r.y = (v.y - stats[1]) * stats[3];
    r.z = 1.0f / fmaxf(v.x, 1e-3f);
    r.w = v.y;
    epre4[e] = r;
}

// ---------------- weight fp16 conversion (once per call) ----------------------
__global__ __launch_bounds__(256) void cvtw_kernel(
    const float* __restrict__ wi, const float* __restrict__ wh,
    __half* __restrict__ wi_h, __half* __restrict__ wh_h)
{
    int i = blockIdx.x * 256 + threadIdx.x;
    if (i < 192 * GINC) wi_h[i] = __float2half(wi[i]);
    if (i < 192 * HIDC) wh_h[i] = __float2half(wh[i]);
}

// ---------------- xn init -----------------------------------------------------
__global__ void initxn_kernel(const float* __restrict__ pm, float* __restrict__ xn) {
    int i = blockIdx.x * 256 + threadIdx.x;
    if (i >= BN) return;
    int b = i / NN, n = i - b * NN;
    xn[i] = pm[(b * HISTC + (HISTC - 1)) * NN + n];
}

// ---------------- CSR build (once per call) -----------------------------------
__global__ void hist_kernel(const int* __restrict__ eidx,
                            int* __restrict__ deg_t, int* __restrict__ deg_s) {
    int e = blockIdx.x * 256 + threadIdx.x;
    if (e >= EE) return;
    atomicAdd(&deg_s[eidx[e]], 1);
    atomicAdd(&deg_t[eidx[EE + e]], 1);
}

__global__ __launch_bounds__(1024) void scan_kernel(
    const int* __restrict__ deg_t, const int* __restrict__ deg_s,
    int* __restrict__ off_t, int* __restrict__ off_s,
    int* __restrict__ cnt_t, int* __restrict__ cnt_s)
{
    __shared__ int pt[1024], ps[1024];
    int tid = threadIdx.x;
    int base = tid * 10;
    int st = 0, ss = 0;
    for (int k = 0; k < 10; k++) {
        int i = base + k;
        if (i < NN) { st += deg_t[i]; ss += deg_s[i]; }
    }
    pt[tid] = st; ps[tid] = ss;
    __syncthreads();
    for (int off = 1; off < 1024; off <<= 1) {
        int vt = (tid >= off) ? pt[tid - off] : 0;
        int vs = (tid >= off) ? ps[tid - off] : 0;
        __syncthreads();
        pt[tid] += vt; ps[tid] += vs;
        __syncthreads();
    }
    int ext = (tid == 0) ? 0 : pt[tid - 1];
    int exs = (tid == 0) ? 0 : ps[tid - 1];
    for (int k = 0; k < 10; k++) {
        int i = base + k;
        if (i < NN) {
            off_t[i] = ext; cnt_t[i] = ext;
            off_s[i] = exs; cnt_s[i] = exs;
            ext += deg_t[i]; exs += deg_s[i];
        }
    }
    if (tid == 0) { off_t[NN] = EE; off_s[NN] = EE; }
}

// epos[e] = {src, tgt, slot_t, slot_s} — single int4 load in edge_kernel
__global__ void fill_kernel(const int* __restrict__ eidx,
                            int* __restrict__ cnt_t, int* __restrict__ cnt_s,
                            int4* __restrict__ epos)
{
    int e = blockIdx.x * 256 + threadIdx.x;
    if (e >= EE) return;
    int s = eidx[e];
    int g = eidx[EE + e];
    int pt = atomicAdd(&cnt_t[g], 1);
    int ps = atomicAdd(&cnt_s[s], 1);
    int4 r; r.x = s; r.y = g; r.z = pt; r.w = ps;
    epos[e] = r;
}

// ---------------- per-step node precompute (fp16 tables) + xn/out finalize ----
__global__ __launch_bounds__(256) void pre_kernel(
    float* __restrict__ xncur, const float* __restrict__ feature, int t,
    const float* __restrict__ xp, const float* __restrict__ fb,
    const float* __restrict__ ew1,
    const float* __restrict__ wmean, const float* __restrict__ wstd,
    __half* __restrict__ preS, __half* __restrict__ preT,
    float2* __restrict__ wind2, float* __restrict__ out)
{
    __shared__ alignas(16) float w1s[18 * EHID];
    for (int i = threadIdx.x; i < 18 * EHID; i += 256) w1s[i] = ew1[i];
    __syncthreads();
    int idx = blockIdx.x * 256 + threadIdx.x;
    if (idx >= BN * 8) return;
    int i = idx >> 3;
    int c = idx & 7;
    int b = i / NN, n = i - b * NN;
    float x0;
    if (t == 0) {
        x0 = xncur[i];
    } else {
        x0 = xp[i] + xp[BN + i] + fb[0];
        if (c == 0) {
            xncur[i] = x0;
            out[(size_t)i * PREDC + (t - 1)] = x0;
        }
    }
    float x[9];
    x[0] = x0;
    {
        const float4* fp = reinterpret_cast<const float4*>(
            feature + (((size_t)b * TSTEP + HISTC + t) * NN + n) * FEX);
        float4 u = fp[0], v = fp[1];
        x[1] = u.x; x[2] = u.y; x[3] = u.z; x[4] = u.w;
        x[5] = v.x; x[6] = v.y; x[7] = v.z; x[8] = v.w;
    }
    float4 aS = {0.f, 0.f, 0.f, 0.f}, aT = {0.f, 0.f, 0.f, 0.f};
    #pragma unroll
    for (int k = 0; k < 9; k++) {
        float4 wS = reinterpret_cast<const float4*>(&w1s[k * EHID])[c];
        float4 wT = reinterpret_cast<const float4*>(&w1s[(9 + k) * EHID])[c];
        aS.x += x[k] * wS.x; aS.y += x[k] * wS.y; aS.z += x[k] * wS.z; aS.w += x[k] * wS.w;
        aT.x += x[k] * wT.x; aT.y += x[k] * wT.y; aT.z += x[k] * wT.z; aT.w += x[k] * wT.w;
    }
    union { uint2 u; __half h[4]; } sv, tv;
    sv.h[0] = __float2half(aS.x); sv.h[1] = __float2half(aS.y);
    sv.h[2] = __float2half(aS.z); sv.h[3] = __float2half(aS.w);
    tv.h[0] = __float2half(aT.x); tv.h[1] = __float2half(aT.y);
    tv.h[2] = __float2half(aT.z); tv.h[3] = __float2half(aT.w);
    reinterpret_cast<uint2*>(preS + (size_t)i * EHID)[c] = sv.u;
    reinterpret_cast<uint2*>(preT + (size_t)i * EHID)[c] = tv.u;
    if (c == 1) {
        float sd0 = fmaxf(wstd[0], 1e-6f), sd1 = fmaxf(wstd[1], 1e-6f);
        float speed = fmaxf(x[7] * sd0 + wmean[0], 0.f);
        float wdir  = (x[8] * sd1 + wmean[1]) * 0.017453292519943295f;
        float2 wv; wv.x = 3.0f * speed; wv.y = wdir;
        wind2[i] = wv;
    }
}

__global__ __launch_bounds__(256) void finalout_kernel(
    const float* __restrict__ xp, const float* __restrict__ fb,
    float* __restrict__ out)
{
    int i = blockIdx.x * 256 + threadIdx.x;
    if (i >= BN) return;
    out[(size_t)i * PREDC + (PREDC - 1)] = xp[i] + xp[BN + i] + fb[0];
}

// ---------------- edge MLP (layers 2,3 + folded n_w) --------------------------
// grid (625, BB). h1 kept packed fp16; layer-2 via v_dot2_f32_f16.
__global__ __launch_bounds__(256) void edge_kernel(
    const int4* __restrict__ epos, const float4* __restrict__ epre4,
    const __half* __restrict__ preS, const __half* __restrict__ preT,
    const float2* __restrict__ wind2,
    const float* __restrict__ ew1, const float* __restrict__ eb1,
    const float* __restrict__ ew2, const float* __restrict__ eb2,
    const float* __restrict__ nw,
    __half* __restrict__ h3t, __half* __restrict__ h3s)
{
    __shared__ alignas(16) __half2 w2h[EOUTC * 16];    // [o][k-pair]
    __shared__ alignas(16) float nws16[EOUTC * 16];    // [o][j] padded
    __shared__ alignas(16) float w18[EHID], w19[EHID], w20[EHID], b1s[EHID];
    __shared__ float b2s[EOUTC];
    for (int i = threadIdx.x; i < EOUTC * 16; i += 256) {
        int o = i >> 4, q = i & 15;
        w2h[i] = __floats2half2_rn(ew2[(2 * q) * EOUTC + o], ew2[(2 * q + 1) * EOUTC + o]);
        int j = q;
        nws16[i] = (j < GOUTC) ? nw[o * GOUTC + j] : 0.f;
    }
    if (threadIdx.x < EHID) {
        w18[threadIdx.x] = ew1[18 * EHID + threadIdx.x];
        w19[threadIdx.x] = ew1[19 * EHID + threadIdx.x];
        w20[threadIdx.x] = ew1[20 * EHID + threadIdx.x];
        b1s[threadIdx.x] = eb1[threadIdx.x];
    }
    if (threadIdx.x < EOUTC) b2s[threadIdx.x] = eb2[threadIdx.x];
    __syncthreads();

    int e = blockIdx.x * 256 + threadIdx.x;
    if (e >= EE) return;
    int b = blockIdx.y;
    int4 epv = epos[e];
    int s = epv.x, g = epv.y, pt = epv.z, ps = epv.w;
    float4 ep = epre4[e];          // {ean0, ean1, 1/dist, direc}

    size_t iS = (size_t)b * NN + s, iT = (size_t)b * NN + g;
    float2 wv2 = wind2[iS];
    float ew = fmaxf(wv2.x * __cosf(fabsf(ep.w - wv2.y)) * ep.z, 0.f);

    union alignas(16) { uint4 u[4]; __half2 h2[16]; } RS, RT;
    {
        const uint4* p;
        p = reinterpret_cast<const uint4*>(preS + iS * EHID);
        RS.u[0] = p[0]; RS.u[1] = p[1]; RS.u[2] = p[2]; RS.u[3] = p[3];
        p = reinterpret_cast<const uint4*>(preT + iT * EHID);
        RT.u[0] = p[0]; RT.u[1] = p[1]; RT.u[2] = p[2]; RT.u[3] = p[3];
    }

    float ean0 = ep.x, ean1 = ep.y;
    __half2 h1h[16];
    #pragma unroll
    for (int q = 0; q < 16; q++) {
        v2f w18q = reinterpret_cast<const v2f*>(w18)[q];
        v2f w19q = reinterpret_cast<const v2f*>(w19)[q];
        v2f w20q = reinterpret_cast<const v2f*>(w20)[q];
        v2f b1q  = reinterpret_cast<const v2f*>(b1s)[q];
        float2 rs = __half22float2(RS.h2[q]);
        float2 rt = __half22float2(RT.h2[q]);
        v2f rsv; rsv.x = rs.x; rsv.y = rs.y;
        v2f rtv; rtv.x = rt.x; rtv.y = rt.y;
        v2f u = w18q * ean0 + w19q * ean1 + b1q + rsv + rtv + w20q * ew;
        v2f sg = sigm2(u);
        h1h[q] = __floats2half2_rn(sg.x, sg.y);
    }

    v2f h3p[7];
    #pragma unroll
    for (int j = 0; j < 7; j++) { h3p[j].x = 0.f; h3p[j].y = 0.f; }

    for (int o = 0; o < EOUTC; o++) {
        union alignas(16) { uint4 u[4]; __half2 h2[16]; } wrow;
        const uint4* wp = reinterpret_cast<const uint4*>(&w2h[o * 16]);
        wrow.u[0] = wp[0]; wrow.u[1] = wp[1]; wrow.u[2] = wp[2]; wrow.u[3] = wp[3];
        float acc = b2s[o];
        #pragma unroll
        for (int q = 0; q < 16; q++) acc = dot2(h1h[q], wrow.h2[q], acc);
        float h2v = sigm(acc);
        const v2f* nr = reinterpret_cast<const v2f*>(&nws16[o * 16]);
        #pragma unroll
        for (int j = 0; j < 7; j++) h3p[j] += nr[j] * h2v;
    }

    union alignas(16) { uint4 u[2]; __half2 h2[8]; } r;
    #pragma unroll
    for (int j = 0; j < 7; j++) r.h2[j] = __floats2half2_rn(h3p[j].x, h3p[j].y);
    r.h2[7] = __floats2half2_rn(0.f, 0.f);
    {
        __half* oT = h3t + ((size_t)b * EE + pt) * 16;
        reinterpret_cast<uint4*>(oT)[0] = r.u[0];
        reinterpret_cast<uint4*>(oT)[1] = r.u[1];
        __half* oS = h3s + ((size_t)b * EE + ps) * 16;
        reinterpret_cast<uint4*>(oS)[0] = r.u[0];
        reinterpret_cast<uint4*>(oS)[1] = r.u[1];
    }
}

// ---------------- gather ------------------------------------------------------
__global__ __launch_bounds__(256) void gather_kernel(
    const __half* __restrict__ h3t, const __half* __restrict__ h3s,
    const int* __restrict__ off_t, const int* __restrict__ off_s,
    float* __restrict__ agg)
{
    int n = (blockIdx.x * 256 + threadIdx.x) >> 6;
    if (n >= NN) return;
    n = __builtin_amdgcn_readfirstlane(n);
    int lane = threadIdx.x & 63;
    int b = lane >> 4, ch = lane & 15;
    const __half* ht = h3t + (size_t)b * EE * 16 + ch;
    const __half* hs = h3s + (size_t)b * EE * 16 + ch;
    float acc = 0.f;
    int i0 = off_t[n], i1 = off_t[n + 1];
    for (int i = i0; i < i1; i++) {
        acc += __half2float(ht[(size_t)i * 16]);
    }
    i0 = off_s[n]; i1 = off_s[n + 1];
    for (int i = i0; i < i1; i++) {
        acc -= __half2float(hs[(size_t)i * 16]);
    }
    agg[((size_t)b * NN + n) * 16 + ch] = acc;
}

// ---------------- node: gnn-out + GRU (fp16 dot2) + fc partial ----------------
// grid (BN/64, 2); wave w of block (.,jb) handles dims [jb*32+w*8, +8).
// h state packed __half2 planes [32][BN].
__global__ __launch_bounds__(256) void node_kernel(
    const float* __restrict__ xncur, const float* __restrict__ feature, int t,
    const float* __restrict__ agg, const float* __restrict__ nb,
    const __half* __restrict__ wi_h, const __half* __restrict__ wh_h,
    const float* __restrict__ bi, const float* __restrict__ bh,
    const float* __restrict__ fw,
    const __half2* __restrict__ hnold, __half2* __restrict__ hnnew,
    float* __restrict__ xp)
{
    __shared__ float xpart[4][64];
    int lane = threadIdx.x & 63;
    int wav  = threadIdx.x >> 6;
    int jb   = blockIdx.y;
    int node = blockIdx.x * 64 + lane;
    int b = node / NN;
    int n = node - b * NN;

    float xc[GINC];
    {
        const float4* ar = reinterpret_cast<const float4*>(agg + (size_t)node * 16);
        float4 a0 = ar[0], a1 = ar[1], a2 = ar[2];
        float a3 = agg[(size_t)node * 16 + 12];
        xc[0] = sigm(a0.x + nb[0]);  xc[1] = sigm(a0.y + nb[1]);
        xc[2] = sigm(a0.z + nb[2]);  xc[3] = sigm(a0.w + nb[3]);
        xc[4] = sigm(a1.x + nb[4]);  xc[5] = sigm(a1.y + nb[5]);
        xc[6] = sigm(a1.z + nb[6]);  xc[7] = sigm(a1.w + nb[7]);
        xc[8] = sigm(a2.x + nb[8]);  xc[9] = sigm(a2.y + nb[9]);
        xc[10] = sigm(a2.z + nb[10]); xc[11] = sigm(a2.w + nb[11]);
        xc[12] = sigm(a3 + nb[12]);
    }
    xc[13] = xncur[node];
    {
        const float4* fp = reinterpret_cast<const float4*>(
            feature + (((size_t)b * TSTEP + HISTC + t) * NN + n) * FEX);
        float4 u = fp[0], v = fp[1];
        xc[14] = u.x; xc[15] = u.y; xc[16] = u.z; xc[17] = u.w;
        xc[18] = v.x; xc[19] = v.y; xc[20] = v.z; xc[21] = v.w;
    }
    __half2 xch[11];
    #pragma unroll
    for (int p = 0; p < 11; p++) xch[p] = __floats2half2_rn(xc[2*p], xc[2*p+1]);

    __half2 hh[32];
    #pragma unroll
    for (int p = 0; p < 32; p++) hh[p] = hnold[(size_t)p * BN + node];

    float xsum = 0.f;
    #pragma unroll
    for (int jj2 = 0; jj2 < 4; jj2++) {
        int j0 = __builtin_amdgcn_readfirstlane(jb * 32 + wav * 8 + jj2 * 2);
        union { __half2 h; __half v[2]; } holdw;
        holdw.h = hnold[(size_t)(j0 >> 1) * BN + node];
        float hnew2[2];
        #pragma unroll
        for (int d = 0; d < 2; d++) {
            int j = j0 + d;
            float ir = bi[j], iz = bi[64 + j], in_ = bi[128 + j];
            const __half2* wr0 = reinterpret_cast<const __half2*>(wi_h + (size_t)j * GINC);
            const __half2* wr1 = reinterpret_cast<const __half2*>(wi_h + (size_t)(64 + j) * GINC);
            const __half2* wr2 = reinterpret_cast<const __half2*>(wi_h + (size_t)(128 + j) * GINC);
            #pragma unroll
            for (int p = 0; p < 11; p++) {
                ir  = dot2(xch[p], wr0[p], ir);
                iz  = dot2(xch[p], wr1[p], iz);
                in_ = dot2(xch[p], wr2[p], in_);
            }
            float hr = bh[j], hz = bh[64 + j], hn_ = bh[128 + j];
            const __half2* vr0 = reinterpret_cast<const __half2*>(wh_h + (size_t)j * HIDC);
            const __half2* vr1 = reinterpret_cast<const __half2*>(wh_h + (size_t)(64 + j) * HIDC);
            const __half2* vr2 = reinterpret_cast<const __half2*>(wh_h + (size_t)(128 + j) * HIDC);
            #pragma unroll
            for (int p = 0; p < 32; p++) {
                hr  = dot2(hh[p], vr0[p], hr);
                hz  = dot2(hh[p], vr1[p], hz);
                hn_ = dot2(hh[p], vr2[p], hn_);
            }
            float r  = sigm(ir + hr);
            float z  = sigm(iz + hz);
            float nn = tanh_fast(in_ + r * hn_);
            float hold = __half2float(holdw.v[d]);
            float hnew = (1.f - z) * nn + z * hold;
            hnew2[d] = hnew;
            xsum += hnew * fw[j];
        }
        hnnew[(size_t)(j0 >> 1) * BN + node] = __floats2half2_rn(hnew2[0], hnew2[1]);
    }
    xpart[wav][lane] = xsum;
    __syncthreads();
    if (wav == 0) {
        float tot = xpart[0][lane] + xpart[1][lane] + xpart[2][lane] + xpart[3][lane];
        xp[(size_t)jb * BN + node] = tot;
    }
}

extern "C" void kernel_launch(void* const* d_in, const int* in_sizes, int n_in,
                              void* d_out, int out_size, void* d_ws, size_t ws_size,
                              hipStream_t stream)
{
    const float* pm    = (const float*)d_in[0];
    const float* feat  = (const float*)d_in[1];
    const float* ea    = (const float*)d_in[2];
    const float* wmean = (const float*)d_in[3];
    const float* wstd  = (const float*)d_in[4];
    const float* ew1   = (const float*)d_in[5];
    const float* eb1   = (const float*)d_in[6];
    const float* ew2   = (const float*)d_in[7];
    const float* eb2   = (const float*)d_in[8];
    const float* nw    = (const float*)d_in[9];
    const float* nb    = (const float*)d_in[10];
    const float* wi    = (const float*)d_in[11];
    const float* wh    = (const float*)d_in[12];
    const float* bi    = (const float*)d_in[13];
    const float* bh    = (const float*)d_in[14];
    const float* fw    = (const float*)d_in[15];
    const float* fb    = (const float*)d_in[16];
    const int*   eidx  = (const int*)d_in[17];
    float* out = (float*)d_out;

    char* w = (char*)d_ws;
    double* partd = (double*)w;                    w += 256 * 4 * sizeof(double);
    float*  stats = (float*)w;                     w += 16 * sizeof(float);
    float4* epre4 = (float4*)w;                    w += (size_t)EE * sizeof(float4);
    float*  xncur = (float*)w;                     w += (size_t)BN * sizeof(float);
    float*  xp    = (float*)w;                     w += (size_t)2 * BN * sizeof(float);
    __half2* hnA  = (__half2*)w;                   w += (size_t)32 * BN * sizeof(__half2);
    __half2* hnB  = (__half2*)w;                   w += (size_t)32 * BN * sizeof(__half2);
    float*  agg13 = (float*)w;                     w += (size_t)BN * 16 * sizeof(float);
    __half* preS  = (__half*)w;                    w += (size_t)BN * EHID * sizeof(__half);
    __half* preT  = (__half*)w;                    w += (size_t)BN * EHID * sizeof(__half);
    float2* wind2 = (float2*)w;                    w += (size_t)BN * sizeof(float2);
    __half* h3t   = (__half*)w;                    w += (size_t)BB * EE * 16 * sizeof(__half);
    __half* h3s   = (__half*)w;                    w += (size_t)BB * EE * 16 * sizeof(__half);
    __half* wi_h  = (__half*)w;                    w += (size_t)192 * GINC * sizeof(__half);
    __half* wh_h  = (__half*)w;                    w += (size_t)192 * HIDC * sizeof(__half);
    int*    deg_t = (int*)w;                       w += NN * sizeof(int);
    int*    deg_s = (int*)w;                       w += NN * sizeof(int);
    int*    off_t = (int*)w;                       w += (NN + 1) * sizeof(int);
    int*    off_s = (int*)w;                       w += (NN + 1) * sizeof(int);
    int*    cnt_t = (int*)w;                       w += NN * sizeof(int);
    int*    cnt_s = (int*)w;                       w += NN * sizeof(int);
    int4*   epos  = (int4*)w;                      w += (size_t)EE * sizeof(int4);

    stats1_kernel<<<256, 256, 0, stream>>>(ea, partd);
    stats2_kernel<<<1, 256, 0, stream>>>(partd, stats);
    edgepre_kernel<<<(EE + 255) / 256, 256, 0, stream>>>(ea, stats, epre4);
    cvtw_kernel<<<(192 * HIDC + 255) / 256, 256, 0, stream>>>(wi, wh, wi_h, wh_h);
    initxn_kernel<<<(BN + 255) / 256, 256, 0, stream>>>(pm, xncur);
    hipMemsetAsync(hnA, 0, (size_t)32 * BN * sizeof(__half2), stream);
    hipMemsetAsync(deg_t, 0, 2 * NN * sizeof(int), stream);
    hist_kernel<<<(EE + 255) / 256, 256, 0, stream>>>(eidx, deg_t, deg_s);
    scan_kernel<<<1, 1024, 0, stream>>>(deg_t, deg_s, off_t, off_s, cnt_t, cnt_s);
    fill_kernel<<<(EE + 255) / 256, 256, 0, stream>>>(eidx, cnt_t, cnt_s, epos);

    for (int t = 0; t < PREDC; t++) {
        const __half2* hnold = (t & 1) ? hnB : hnA;
        __half2*       hnnew = (t & 1) ? hnA : hnB;
        pre_kernel<<<(BN * 8 + 255) / 256, 256, 0, stream>>>(
            xncur, feat, t, xp, fb, ew1, wmean, wstd, preS, preT, wind2, out);
        edge_kernel<<<dim3((EE + 255) / 256, BB), 256, 0, stream>>>(
            epos, epre4, preS, preT, wind2,
            ew1, eb1, ew2, eb2, nw, h3t, h3s);
        gather_kernel<<<(NN * 64 + 255) / 256, 256, 0, stream>>>(
            h3t, h3s, off_t, off_s, agg13);
        node_kernel<<<dim3(BN / 64, 2), 256, 0, stream>>>(
            xncur, feat, t, agg13, nb, wi_h, wh_h, bi, bh, fw, hnold, hnnew, xp);
    }
    finalout_kernel<<<(BN + 255) / 256, 256, 0, stream>>>(xp, fb, out);
}

// Round 9
// 1229.940 us; speedup vs baseline: 1.8713x; 1.0710x over previous
//
#include <hip/hip_runtime.h>
#include <hip/hip_fp16.h>
#include <cstddef>

#define BB    4
#define NN    10000
#define EE    160000
#define BN    40000      // BB*NN
#define HISTC 8
#define PREDC 12
#define TSTEP 20         // HIST+PRED
#define FEX   8
#define HIDC  64
#define EHID  32
#define EOUTC 30
#define GOUTC 13
#define GINC  22         // GOUTC + 9

typedef float v2f __attribute__((ext_vector_type(2)));
typedef _Float16 v2h __attribute__((ext_vector_type(2)));

__device__ __forceinline__ float fast_rcp(float x) { return __builtin_amdgcn_rcpf(x); }
__device__ __forceinline__ float sigm(float x) {
    return fast_rcp(1.0f + __expf(-x));
}
__device__ __forceinline__ v2f sigm2(v2f x) {
    v2f r; r.x = sigm(x.x); r.y = sigm(x.y); return r;
}
__device__ __forceinline__ float tanh_fast(float x) {
    x = fminf(fmaxf(x, -15.0f), 15.0f);
    float e = __expf(2.0f * x);
    return (e - 1.0f) * fast_rcp(e + 1.0f);
}

// packed fp16 dot with fp32 accumulate (v_dot2_f32_f16)
__device__ __forceinline__ float dot2(__half2 a, __half2 b, float c) {
#if __has_builtin(__builtin_amdgcn_fdot2)
    union { __half2 h; v2h v; } ua, ub;
    ua.h = a; ub.h = b;
    return __builtin_amdgcn_fdot2(ua.v, ub.v, c, false);
#else
    float2 fa = __half22float2(a), fb = __half22float2(b);
    return c + fa.x * fb.x + fa.y * fb.y;
#endif
}

// ---------------- edge_attr stats ---------------------------------------------
__global__ __launch_bounds__(256) void stats1_kernel(const float* __restrict__ ea,
                                                     double* __restrict__ part) {
    __shared__ double sm[256][4];
    int tid = threadIdx.x;
    double s0 = 0, s1 = 0, q0 = 0, q1 = 0;
    for (int e = blockIdx.x * 256 + tid; e < EE; e += 256 * 256) {
        float2 v = reinterpret_cast<const float2*>(ea)[e];
        double v0 = (double)v.x, v1 = (double)v.y;
        s0 += v0; q0 += v0 * v0;
        s1 += v1; q1 += v1 * v1;
    }
    sm[tid][0] = s0; sm[tid][1] = s1; sm[tid][2] = q0; sm[tid][3] = q1;
    __syncthreads();
    for (int off = 128; off > 0; off >>= 1) {
        if (tid < off)
            for (int k = 0; k < 4; k++) sm[tid][k] += sm[tid + off][k];
        __syncthreads();
    }
    if (tid == 0) {
        part[blockIdx.x * 4 + 0] = sm[0][0];
        part[blockIdx.x * 4 + 1] = sm[0][1];
        part[blockIdx.x * 4 + 2] = sm[0][2];
        part[blockIdx.x * 4 + 3] = sm[0][3];
    }
}

__global__ __launch_bounds__(256) void stats2_kernel(const double* __restrict__ part,
                                                     float* __restrict__ stats) {
    __shared__ double sm[256][4];
    int tid = threadIdx.x;
    sm[tid][0] = part[tid * 4 + 0];
    sm[tid][1] = part[tid * 4 + 1];
    sm[tid][2] = part[tid * 4 + 2];
    sm[tid][3] = part[tid * 4 + 3];
    __syncthreads();
    for (int off = 128; off > 0; off >>= 1) {
        if (tid < off)
            for (int k = 0; k < 4; k++) sm[tid][k] += sm[tid + off][k];
        __syncthreads();
    }
    if (tid == 0) {
        double m0 = sm[0][0] / EE, m1 = sm[0][1] / EE;
        double v0 = (sm[0][2] - sm[0][0] * sm[0][0] / EE) / (double)(EE - 1);
        double v1 = (sm[0][3] - sm[0][1] * sm[0][1] / EE) / (double)(EE - 1);
        float sd0 = fmaxf((float)sqrt(v0 > 0 ? v0 : 0.0), 1e-6f);
        float sd1 = fmaxf((float)sqrt(v1 > 0 ? v1 : 0.0), 1e-6f);
        stats[0] = (float)m0; stats[1] = (float)m1;
        stats[2] = 1.0f / sd0; stats[3] = 1.0f / sd1;
    }
}

// ---------------- per-edge precompute -----------------------------------------
__global__ __launch_bounds__(256) void edgepre_kernel(
    const float* __restrict__ ea, const float* __restrict__ stats,
    float4* __restrict__ epre4)
{
    int e = blockIdx.x * 256 + threadIdx.x;
    if (e >= EE) return;
    float2 v = reinterpret_cast<const float2*>(ea)[e];
    float4 r;
    r.x = (v.x - stats[0]) * stats[2];
    r.y = (v.y - stats[1]) * stats[3];
    r.z = 1.0f / fmaxf(v.x, 1e-3f);
    r.w = v.y;
    epre4[e] = r;
}

// ---------------- weight fp16 conversion (once per call) ----------------------
__global__ __launch_bounds__(256) void cvtw_kernel(
    const float* __restrict__ wi, const float* __restrict__ wh,
    __half* __restrict__ wi_h, __half* __restrict__ wh_h)
{
    int i = blockIdx.x * 256 + threadIdx.x;
    if (i < 192 * GINC) wi_h[i] = __float2half(wi[i]);
    if (i < 192 * HIDC) wh_h[i] = __float2half(wh[i]);
}

// ---------------- xn init -----------------------------------------------------
__global__ void initxn_kernel(const float* __restrict__ pm, float* __restrict__ xn) {
    int i = blockIdx.x * 256 + threadIdx.x;
    if (i >= BN) return;
    int b = i / NN, n = i - b * NN;
    xn[i] = pm[(b * HISTC + (HISTC - 1)) * NN + n];
}

// ---------------- CSR build (once per call) -----------------------------------
__global__ void hist_kernel(const int* __restrict__ eidx,
                            int* __restrict__ deg_t, int* __restrict__ deg_s) {
    int e = blockIdx.x * 256 + threadIdx.x;
    if (e >= EE) return;
    atomicAdd(&deg_s[eidx[e]], 1);
    atomicAdd(&deg_t[eidx[EE + e]], 1);
}

__global__ __launch_bounds__(1024) void scan_kernel(
    const int* __restrict__ deg_t, const int* __restrict__ deg_s,
    int* __restrict__ off_t, int* __restrict__ off_s,
    int* __restrict__ cnt_t, int* __restrict__ cnt_s)
{
    __shared__ int pt[1024], ps[1024];
    int tid = threadIdx.x;
    int base = tid * 10;
    int st = 0, ss = 0;
    for (int k = 0; k < 10; k++) {
        int i = base + k;
        if (i < NN) { st += deg_t[i]; ss += deg_s[i]; }
    }
    pt[tid] = st; ps[tid] = ss;
    __syncthreads();
    for (int off = 1; off < 1024; off <<= 1) {
        int vt = (tid >= off) ? pt[tid - off] : 0;
        int vs = (tid >= off) ? ps[tid - off] : 0;
        __syncthreads();
        pt[tid] += vt; ps[tid] += vs;
        __syncthreads();
    }
    int ext = (tid == 0) ? 0 : pt[tid - 1];
    int exs = (tid == 0) ? 0 : ps[tid - 1];
    for (int k = 0; k < 10; k++) {
        int i = base + k;
        if (i < NN) {
            off_t[i] = ext; cnt_t[i] = ext;
            off_s[i] = exs; cnt_s[i] = exs;
            ext += deg_t[i]; exs += deg_s[i];
        }
    }
    if (tid == 0) { off_t[NN] = EE; off_s[NN] = EE; }
}

__global__ void fill_kernel(const int* __restrict__ eidx,
                            int* __restrict__ cnt_t, int* __restrict__ cnt_s,
                            int4* __restrict__ epos)
{
    int e = blockIdx.x * 256 + threadIdx.x;
    if (e >= EE) return;
    int s = eidx[e];
    int g = eidx[EE + e];
    int pt = atomicAdd(&cnt_t[g], 1);
    int ps = atomicAdd(&cnt_s[s], 1);
    int4 r; r.x = s; r.y = g; r.z = pt; r.w = ps;
    epos[e] = r;
}

// permute into tgt-slot order: eT[slot]={src,tgt,pos_s}; epreT[slot]=epre4[e]
__global__ void perm_kernel(const int4* __restrict__ epos,
                            const float4* __restrict__ epre4,
                            int4* __restrict__ eT, float4* __restrict__ epreT)
{
    int e = blockIdx.x * 256 + threadIdx.x;
    if (e >= EE) return;
    int4 p = epos[e];
    int slot = p.z;
    int4 r; r.x = p.x; r.y = p.y; r.z = p.w; r.w = 0;
    eT[slot] = r;
    epreT[slot] = epre4[e];
}

// ---------------- per-step node precompute (fp16 tables) + xn/out finalize ----
__global__ __launch_bounds__(256) void pre_kernel(
    float* __restrict__ xncur, const float* __restrict__ feature, int t,
    const float* __restrict__ xp, const float* __restrict__ fb,
    const float* __restrict__ ew1,
    const float* __restrict__ wmean, const float* __restrict__ wstd,
    __half* __restrict__ preS, __half* __restrict__ preT,
    float2* __restrict__ wind2, float* __restrict__ out)
{
    __shared__ alignas(16) float w1s[18 * EHID];
    for (int i = threadIdx.x; i < 18 * EHID; i += 256) w1s[i] = ew1[i];
    __syncthreads();
    int idx = blockIdx.x * 256 + threadIdx.x;
    if (idx >= BN * 8) return;
    int i = idx >> 3;
    int c = idx & 7;
    int b = i / NN, n = i - b * NN;
    float x0;
    if (t == 0) {
        x0 = xncur[i];
    } else {
        x0 = xp[i] + xp[BN + i] + fb[0];
        if (c == 0) {
            xncur[i] = x0;
            out[(size_t)i * PREDC + (t - 1)] = x0;
        }
    }
    float x[9];
    x[0] = x0;
    {
        const float4* fp = reinterpret_cast<const float4*>(
            feature + (((size_t)b * TSTEP + HISTC + t) * NN + n) * FEX);
        float4 u = fp[0], v = fp[1];
        x[1] = u.x; x[2] = u.y; x[3] = u.z; x[4] = u.w;
        x[5] = v.x; x[6] = v.y; x[7] = v.z; x[8] = v.w;
    }
    float4 aS = {0.f, 0.f, 0.f, 0.f}, aT = {0.f, 0.f, 0.f, 0.f};
    #pragma unroll
    for (int k = 0; k < 9; k++) {
        float4 wS = reinterpret_cast<const float4*>(&w1s[k * EHID])[c];
        float4 wT = reinterpret_cast<const float4*>(&w1s[(9 + k) * EHID])[c];
        aS.x += x[k] * wS.x; aS.y += x[k] * wS.y; aS.z += x[k] * wS.z; aS.w += x[k] * wS.w;
        aT.x += x[k] * wT.x; aT.y += x[k] * wT.y; aT.z += x[k] * wT.z; aT.w += x[k] * wT.w;
    }
    union { uint2 u; __half h[4]; } sv, tv;
    sv.h[0] = __float2half(aS.x); sv.h[1] = __float2half(aS.y);
    sv.h[2] = __float2half(aS.z); sv.h[3] = __float2half(aS.w);
    tv.h[0] = __float2half(aT.x); tv.h[1] = __float2half(aT.y);
    tv.h[2] = __float2half(aT.z); tv.h[3] = __float2half(aT.w);
    reinterpret_cast<uint2*>(preS + (size_t)i * EHID)[c] = sv.u;
    reinterpret_cast<uint2*>(preT + (size_t)i * EHID)[c] = tv.u;
    if (c == 1) {
        float sd0 = fmaxf(wstd[0], 1e-6f), sd1 = fmaxf(wstd[1], 1e-6f);
        float speed = fmaxf(x[7] * sd0 + wmean[0], 0.f);
        float wdir  = (x[8] * sd1 + wmean[1]) * 0.017453292519943295f;
        float2 wv; wv.x = 3.0f * speed; wv.y = wdir;
        wind2[i] = wv;
    }
}

__global__ __launch_bounds__(256) void finalout_kernel(
    const float* __restrict__ xp, const float* __restrict__ fb,
    float* __restrict__ out)
{
    int i = blockIdx.x * 256 + threadIdx.x;
    if (i >= BN) return;
    out[(size_t)i * PREDC + (PREDC - 1)] = xp[i] + xp[BN + i] + fb[0];
}

// ---------------- edge MLP in tgt-slot order ----------------------------------
// grid (625, BB); thread i = slot i. h3t write coalesced; preT reads sequential.
__global__ __launch_bounds__(256) void edge_kernel(
    const int4* __restrict__ eT, const float4* __restrict__ epreT,
    const __half* __restrict__ preS, const __half* __restrict__ preT,
    const float2* __restrict__ wind2,
    const float* __restrict__ ew1, const float* __restrict__ eb1,
    const float* __restrict__ ew2, const float* __restrict__ eb2,
    const float* __restrict__ nw,
    __half* __restrict__ h3t, __half* __restrict__ h3s)
{
    __shared__ alignas(16) __half2 w2h[EOUTC * 16];    // [o][k-pair]
    __shared__ alignas(16) float nws16[EOUTC * 16];    // [o][j] padded
    __shared__ alignas(16) float w18[EHID], w19[EHID], w20[EHID], b1s[EHID];
    __shared__ float b2s[EOUTC];
    for (int i = threadIdx.x; i < EOUTC * 16; i += 256) {
        int o = i >> 4, q = i & 15;
        w2h[i] = __floats2half2_rn(ew2[(2 * q) * EOUTC + o], ew2[(2 * q + 1) * EOUTC + o]);
        nws16[i] = (q < GOUTC) ? nw[o * GOUTC + q] : 0.f;
    }
    if (threadIdx.x < EHID) {
        w18[threadIdx.x] = ew1[18 * EHID + threadIdx.x];
        w19[threadIdx.x] = ew1[19 * EHID + threadIdx.x];
        w20[threadIdx.x] = ew1[20 * EHID + threadIdx.x];
        b1s[threadIdx.x] = eb1[threadIdx.x];
    }
    if (threadIdx.x < EOUTC) b2s[threadIdx.x] = eb2[threadIdx.x];
    __syncthreads();

    int i = blockIdx.x * 256 + threadIdx.x;   // slot
    if (i >= EE) return;
    int b = blockIdx.y;
    int4 et = eT[i];
    int s = et.x, g = et.y, ps = et.z;
    float4 ep = epreT[i];          // {ean0, ean1, 1/dist, direc}

    size_t iS = (size_t)b * NN + s, iT = (size_t)b * NN + g;
    float2 wv2 = wind2[iS];
    float ew = fmaxf(wv2.x * __cosf(fabsf(ep.w - wv2.y)) * ep.z, 0.f);

    union alignas(16) { uint4 u[4]; __half2 h2[16]; } RS, RT;
    {
        const uint4* p;
        p = reinterpret_cast<const uint4*>(preS + iS * EHID);
        RS.u[0] = p[0]; RS.u[1] = p[1]; RS.u[2] = p[2]; RS.u[3] = p[3];
        p = reinterpret_cast<const uint4*>(preT + iT * EHID);
        RT.u[0] = p[0]; RT.u[1] = p[1]; RT.u[2] = p[2]; RT.u[3] = p[3];
    }

    float ean0 = ep.x, ean1 = ep.y;
    __half2 h1h[16];
    #pragma unroll
    for (int q = 0; q < 16; q++) {
        v2f w18q = reinterpret_cast<const v2f*>(w18)[q];
        v2f w19q = reinterpret_cast<const v2f*>(w19)[q];
        v2f w20q = reinterpret_cast<const v2f*>(w20)[q];
        v2f b1q  = reinterpret_cast<const v2f*>(b1s)[q];
        float2 rs = __half22float2(RS.h2[q]);
        float2 rt = __half22float2(RT.h2[q]);
        v2f rsv; rsv.x = rs.x; rsv.y = rs.y;
        v2f rtv; rtv.x = rt.x; rtv.y = rt.y;
        v2f u = w18q * ean0 + w19q * ean1 + b1q + rsv + rtv + w20q * ew;
        v2f sg = sigm2(u);
        h1h[q] = __floats2half2_rn(sg.x, sg.y);
    }

    v2f h3p[7];
    #pragma unroll
    for (int j = 0; j < 7; j++) { h3p[j].x = 0.f; h3p[j].y = 0.f; }

    for (int o = 0; o < EOUTC; o++) {
        union alignas(16) { uint4 u[4]; __half2 h2[16]; } wrow;
        const uint4* wp = reinterpret_cast<const uint4*>(&w2h[o * 16]);
        wrow.u[0] = wp[0]; wrow.u[1] = wp[1]; wrow.u[2] = wp[2]; wrow.u[3] = wp[3];
        float acc = b2s[o];
        #pragma unroll
        for (int q = 0; q < 16; q++) acc = dot2(h1h[q], wrow.h2[q], acc);
        float h2v = sigm(acc);
        const v2f* nr = reinterpret_cast<const v2f*>(&nws16[o * 16]);
        #pragma unroll
        for (int j = 0; j < 7; j++) h3p[j] += nr[j] * h2v;
    }

    union alignas(16) { uint4 u[2]; __half2 h2[8]; } r;
    #pragma unroll
    for (int j = 0; j < 7; j++) r.h2[j] = __floats2half2_rn(h3p[j].x, h3p[j].y);
    r.h2[7] = __floats2half2_rn(0.f, 0.f);
    {
        __half* oT = h3t + ((size_t)b * EE + i) * 16;     // coalesced
        reinterpret_cast<uint4*>(oT)[0] = r.u[0];
        reinterpret_cast<uint4*>(oT)[1] = r.u[1];
        __half* oS = h3s + ((size_t)b * EE + ps) * 16;    // scattered
        reinterpret_cast<uint4*>(oS)[0] = r.u[0];
        reinterpret_cast<uint4*>(oS)[1] = r.u[1];
    }
}

// ---------------- gather ------------------------------------------------------
__global__ __launch_bounds__(256) void gather_kernel(
    const __half* __restrict__ h3t, const __half* __restrict__ h3s,
    const int* __restrict__ off_t, const int* __restrict__ off_s,
    float* __restrict__ agg)
{
    int n = (blockIdx.x * 256 + threadIdx.x) >> 6;
    if (n >= NN) return;
    n = __builtin_amdgcn_readfirstlane(n);
    int lane = threadIdx.x & 63;
    int b = lane >> 4, ch = lane & 15;
    const __half* ht = h3t + (size_t)b * EE * 16 + ch;
    const __half* hs = h3s + (size_t)b * EE * 16 + ch;
    float acc = 0.f;
    int i0 = off_t[n], i1 = off_t[n + 1];
    for (int i = i0; i < i1; i++) {
        acc += __half2float(ht[(size_t)i * 16]);
    }
    i0 = off_s[n]; i1 = off_s[n + 1];
    for (int i = i0; i < i1; i++) {
        acc -= __half2float(hs[(size_t)i * 16]);
    }
    agg[((size_t)b * NN + n) * 16 + ch] = acc;
}

// ---------------- node: gnn-out + GRU (fp16 dot2) + fc partial ----------------
__global__ __launch_bounds__(256) void node_kernel(
    const float* __restrict__ xncur, const float* __restrict__ feature, int t,
    const float* __restrict__ agg, const float* __restrict__ nb,
    const __half* __restrict__ wi_h, const __half* __restrict__ wh_h,
    const float* __restrict__ bi, const float* __restrict__ bh,
    const float* __restrict__ fw,
    const __half2* __restrict__ hnold, __half2* __restrict__ hnnew,
    float* __restrict__ xp)
{
    __shared__ float xpart[4][64];
    int lane = threadIdx.x & 63;
    int wav  = threadIdx.x >> 6;
    int jb   = blockIdx.y;
    int node = blockIdx.x * 64 + lane;
    int b = node / NN;
    int n = node - b * NN;

    float xc[GINC];
    {
        const float4* ar = reinterpret_cast<const float4*>(agg + (size_t)node * 16);
        float4 a0 = ar[0], a1 = ar[1], a2 = ar[2];
        float a3 = agg[(size_t)node * 16 + 12];
        xc[0] = sigm(a0.x + nb[0]);  xc[1] = sigm(a0.y + nb[1]);
        xc[2] = sigm(a0.z + nb[2]);  xc[3] = sigm(a0.w + nb[3]);
        xc[4] = sigm(a1.x + nb[4]);  xc[5] = sigm(a1.y + nb[5]);
        xc[6] = sigm(a1.z + nb[6]);  xc[7] = sigm(a1.w + nb[7]);
        xc[8] = sigm(a2.x + nb[8]);  xc[9] = sigm(a2.y + nb[9]);
        xc[10] = sigm(a2.z + nb[10]); xc[11] = sigm(a2.w + nb[11]);
        xc[12] = sigm(a3 + nb[12]);
    }
    xc[13] = xncur[node];
    {
        const float4* fp = reinterpret_cast<const float4*>(
            feature + (((size_t)b * TSTEP + HISTC + t) * NN + n) * FEX);
        float4 u = fp[0], v = fp[1];
        xc[14] = u.x; xc[15] = u.y; xc[16] = u.z; xc[17] = u.w;
        xc[18] = v.x; xc[19] = v.y; xc[20] = v.z; xc[21] = v.w;
    }
    __half2 xch[11];
    #pragma unroll
    for (int p = 0; p < 11; p++) xch[p] = __floats2half2_rn(xc[2*p], xc[2*p+1]);

    __half2 hh[32];
    #pragma unroll
    for (int p = 0; p < 32; p++) hh[p] = hnold[(size_t)p * BN + node];

    float xsum = 0.f;
    #pragma unroll
    for (int jj2 = 0; jj2 < 4; jj2++) {
        int j0 = __builtin_amdgcn_readfirstlane(jb * 32 + wav * 8 + jj2 * 2);
        union { __half2 h; __half v[2]; } holdw;
        holdw.h = hnold[(size_t)(j0 >> 1) * BN + node];
        float hnew2[2];
        #pragma unroll
        for (int d = 0; d < 2; d++) {
            int j = j0 + d;
            float ir = bi[j], iz = bi[64 + j], in_ = bi[128 + j];
            const __half2* wr0 = reinterpret_cast<const __half2*>(wi_h + (size_t)j * GINC);
            const __half2* wr1 = reinterpret_cast<const __half2*>(wi_h + (size_t)(64 + j) * GINC);
            const __half2* wr2 = reinterpret_cast<const __half2*>(wi_h + (size_t)(128 + j) * GINC);
            #pragma unroll
            for (int p = 0; p < 11; p++) {
                ir  = dot2(xch[p], wr0[p], ir);
                iz  = dot2(xch[p], wr1[p], iz);
                in_ = dot2(xch[p], wr2[p], in_);
            }
            float hr = bh[j], hz = bh[64 + j], hn_ = bh[128 + j];
            const __half2* vr0 = reinterpret_cast<const __half2*>(wh_h + (size_t)j * HIDC);
            const __half2* vr1 = reinterpret_cast<const __half2*>(wh_h + (size_t)(64 + j) * HIDC);
            const __half2* vr2 = reinterpret_cast<const __half2*>(wh_h + (size_t)(128 + j) * HIDC);
            #pragma unroll
            for (int p = 0; p < 32; p++) {
                hr  = dot2(hh[p], vr0[p], hr);
                hz  = dot2(hh[p], vr1[p], hz);
                hn_ = dot2(hh[p], vr2[p], hn_);
            }
            float r  = sigm(ir + hr);
            float z  = sigm(iz + hz);
            float nn = tanh_fast(in_ + r * hn_);
            float hold = __half2float(holdw.v[d]);
            float hnew = (1.f - z) * nn + z * hold;
            hnew2[d] = hnew;
            xsum += hnew * fw[j];
        }
        hnnew[(size_t)(j0 >> 1) * BN + node] = __floats2half2_rn(hnew2[0], hnew2[1]);
    }
    xpart[wav][lane] = xsum;
    __syncthreads();
    if (wav == 0) {
        float tot = xpart[0][lane] + xpart[1][lane] + xpart[2][lane] + xpart[3][lane];
        xp[(size_t)jb * BN + node] = tot;
    }
}

extern "C" void kernel_launch(void* const* d_in, const int* in_sizes, int n_in,
                              void* d_out, int out_size, void* d_ws, size_t ws_size,
                              hipStream_t stream)
{
    const float* pm    = (const float*)d_in[0];
    const float* feat  = (const float*)d_in[1];
    const float* ea    = (const float*)d_in[2];
    const float* wmean = (const float*)d_in[3];
    const float* wstd  = (const float*)d_in[4];
    const float* ew1   = (const float*)d_in[5];
    const float* eb1   = (const float*)d_in[6];
    const float* ew2   = (const float*)d_in[7];
    const float* eb2   = (const float*)d_in[8];
    const float* nw    = (const float*)d_in[9];
    const float* nb    = (const float*)d_in[10];
    const float* wi    = (const float*)d_in[11];
    const float* wh    = (const float*)d_in[12];
    const float* bi    = (const float*)d_in[13];
    const float* bh    = (const float*)d_in[14];
    const float* fw    = (const float*)d_in[15];
    const float* fb    = (const float*)d_in[16];
    const int*   eidx  = (const int*)d_in[17];
    float* out = (float*)d_out;

    char* w = (char*)d_ws;
    double* partd = (double*)w;                    w += 256 * 4 * sizeof(double);
    float*  stats = (float*)w;                     w += 16 * sizeof(float);
    float4* epre4 = (float4*)w;                    w += (size_t)EE * sizeof(float4);
    float4* epreT = (float4*)w;                    w += (size_t)EE * sizeof(float4);
    float*  xncur = (float*)w;                     w += (size_t)BN * sizeof(float);
    float*  xp    = (float*)w;                     w += (size_t)2 * BN * sizeof(float);
    __half2* hnA  = (__half2*)w;                   w += (size_t)32 * BN * sizeof(__half2);
    __half2* hnB  = (__half2*)w;                   w += (size_t)32 * BN * sizeof(__half2);
    float*  agg13 = (float*)w;                     w += (size_t)BN * 16 * sizeof(float);
    __half* preS  = (__half*)w;                    w += (size_t)BN * EHID * sizeof(__half);
    __half* preT  = (__half*)w;                    w += (size_t)BN * EHID * sizeof(__half);
    float2* wind2 = (float2*)w;                    w += (size_t)BN * sizeof(float2);
    __half* h3t   = (__half*)w;                    w += (size_t)BB * EE * 16 * sizeof(__half);
    __half* h3s   = (__half*)w;                    w += (size_t)BB * EE * 16 * sizeof(__half);
    __half* wi_h  = (__half*)w;                    w += (size_t)192 * GINC * sizeof(__half);
    __half* wh_h  = (__half*)w;                    w += (size_t)192 * HIDC * sizeof(__half);
    int*    deg_t = (int*)w;                       w += NN * sizeof(int);
    int*    deg_s = (int*)w;                       w += NN * sizeof(int);
    int*    off_t = (int*)w;                       w += (NN + 1) * sizeof(int);
    int*    off_s = (int*)w;                       w += (NN + 1) * sizeof(int);
    int*    cnt_t = (int*)w;                       w += NN * sizeof(int);
    int*    cnt_s = (int*)w;                       w += NN * sizeof(int);
    int4*   epos  = (int4*)w;                      w += (size_t)EE * sizeof(int4);
    int4*   eT    = (int4*)w;                      w += (size_t)EE * sizeof(int4);

    stats1_kernel<<<256, 256, 0, stream>>>(ea, partd);
    stats2_kernel<<<1, 256, 0, stream>>>(partd, stats);
    edgepre_kernel<<<(EE + 255) / 256, 256, 0, stream>>>(ea, stats, epre4);
    cvtw_kernel<<<(192 * HIDC + 255) / 256, 256, 0, stream>>>(wi, wh, wi_h, wh_h);
    initxn_kernel<<<(BN + 255) / 256, 256, 0, stream>>>(pm, xncur);
    hipMemsetAsync(hnA, 0, (size_t)32 * BN * sizeof(__half2), stream);
    hipMemsetAsync(deg_t, 0, 2 * NN * sizeof(int), stream);
    hist_kernel<<<(EE + 255) / 256, 256, 0, stream>>>(eidx, deg_t, deg_s);
    scan_kernel<<<1, 1024, 0, stream>>>(deg_t, deg_s, off_t, off_s, cnt_t, cnt_s);
    fill_kernel<<<(EE + 255) / 256, 256, 0, stream>>>(eidx, cnt_t, cnt_s, epos);
    perm_kernel<<<(EE + 255) / 256, 256, 0, stream>>>(epos, epre4, eT, epreT);

    for (int t = 0; t < PREDC; t++) {
        const __half2* hnold = (t & 1) ? hnB : hnA;
        __half2*       hnnew = (t & 1) ? hnA : hnB;
        pre_kernel<<<(BN * 8 + 255) / 256, 256, 0, stream>>>(
            xncur, feat, t, xp, fb, ew1, wmean, wstd, preS, preT, wind2, out);
        edge_kernel<<<dim3((EE + 255) / 256, BB), 256, 0, stream>>>(
            eT, epreT, preS, preT, wind2,
            ew1, eb1, ew2, eb2, nw, h3t, h3s);
        gather_kernel<<<(NN * 64 + 255) / 256, 256, 0, stream>>>(
            h3t, h3s, off_t, off_s, agg13);
        node_kernel<<<dim3(BN / 64, 2), 256, 0, stream>>>(
            xncur, feat, t, agg13, nb, wi_h, wh_h, bi, bh, fw, hnold, hnnew, xp);
    }
    finalout_kernel<<<(BN + 255) / 256, 256, 0, stream>>>(xp, fb, out);
}